// Round 14
// baseline (894.995 us; speedup 1.0000x reference)
//
#include <hip/hip_runtime.h>
#include <math.h>

#define VOCABSZ 50257
#define VPAD 50432
#define DMODEL 768
#define NHEAD 12
#define NLAYER 4
#define SEQ 1024
#define BATCH 2
#define DHEAD 64
#define DFFN 3072
#define BT (BATCH * SEQ)
#define NBH (BATCH * NHEAD)

typedef __attribute__((ext_vector_type(8))) short bf16x8;
typedef __attribute__((ext_vector_type(4))) float f32x4;

__device__ __forceinline__ ushort f2bf(float f) {
  uint u = __builtin_bit_cast(uint, f);
  u = (u + 0x7fffu + ((u >> 16) & 1u)) >> 16;
  return (ushort)u;
}

__device__ __forceinline__ float bf2f(ushort u) {
  uint x = ((uint)u) << 16;
  return __builtin_bit_cast(float, x);
}

__device__ __forceinline__ void gl_lds16(const ushort* g, ushort* l) {
  __builtin_amdgcn_global_load_lds(
      (const __attribute__((address_space(1))) void*)g,
      (__attribute__((address_space(3))) void*)l, 16, 0, 0);
}

// ------------------------------------------------------------- conversions
// wq/wk/wv (NL,D,D) fp32 -> wqkv_b (NL, 3D, D) bf16, one launch.
__global__ __launch_bounds__(256) void conv_qkv3_kernel(
    const float* __restrict__ wq, const float* __restrict__ wk,
    const float* __restrict__ wv, ushort* __restrict__ dst) {
  const int per4 = DMODEL * DMODEL / 4;
  const int total = NLAYER * per4;
  int i = blockIdx.x * 256 + threadIdx.x;
  if (i >= 3 * total) return;
  int which = i / total;
  int rem = i - which * total;
  const float* src = (which == 0) ? wq : (which == 1) ? wk : wv;
  int layer = rem / per4, r2 = rem % per4;
  float4 v = reinterpret_cast<const float4*>(src)[rem];
  reinterpret_cast<ushort4*>(dst)[(size_t)layer * (3 * per4) + which * per4 +
                                  r2] =
      make_ushort4(f2bf(v.x), f2bf(v.y), f2bf(v.z), f2bf(v.w));
}

// wo + fw1 + fw2 fp32 -> bf16, one launch (range select).
__global__ __launch_bounds__(256) void conv3_kernel(
    const float* __restrict__ wo, ushort* __restrict__ wo_b,
    const float* __restrict__ fw1, ushort* __restrict__ fw1_b,
    const float* __restrict__ fw2, ushort* __restrict__ fw2_b) {
  const int n1 = NLAYER * DMODEL * DMODEL / 4;
  const int nf = NLAYER * DFFN * DMODEL / 4;
  int i = blockIdx.x * 256 + threadIdx.x;
  const float* src;
  ushort* dst;
  int idx;
  if (i < n1) {
    src = wo; dst = wo_b; idx = i;
  } else if (i < n1 + nf) {
    src = fw1; dst = fw1_b; idx = i - n1;
  } else if (i < n1 + 2 * nf) {
    src = fw2; dst = fw2_b; idx = i - n1 - nf;
  } else {
    return;
  }
  float4 v = reinterpret_cast<const float4*>(src)[idx];
  reinterpret_cast<ushort4*>(dst)[idx] =
      make_ushort4(f2bf(v.x), f2bf(v.y), f2bf(v.z), f2bf(v.w));
}

__global__ __launch_bounds__(256) void conv_embed_kernel(
    const float* __restrict__ emb, ushort* __restrict__ dst) {
  int i = blockIdx.x * 256 + threadIdx.x;
  if (i >= VPAD * DMODEL / 4) return;
  int row = (i * 4) / DMODEL;
  ushort4 o = make_ushort4(0, 0, 0, 0);
  if (row < VOCABSZ) {
    float4 v = reinterpret_cast<const float4*>(emb)[i];
    o = make_ushort4(f2bf(v.x), f2bf(v.y), f2bf(v.z), f2bf(v.w));
  }
  reinterpret_cast<ushort4*>(dst)[i] = o;
}

// --------------- layernorm (+ fused split-K reduce / embedding, bf16 parts)
template <int KS, bool RBIAS, bool EMB>
__global__ __launch_bounds__(256) void ln_kernel(
    float* __restrict__ h, const ushort* __restrict__ part,
    const float* __restrict__ rb, const int* __restrict__ tok,
    const float* __restrict__ emb, const float* __restrict__ pos,
    const float* __restrict__ g, const float* __restrict__ bta,
    ushort* __restrict__ o) {
  __shared__ float red[8];
  int row = blockIdx.x;
  int tid = threadIdx.x;
  float* xr = h + (size_t)row * DMODEL;
  const float* er = nullptr;
  const float* pr = nullptr;
  if (EMB) {
    er = emb + (size_t)tok[row] * DMODEL;
    pr = pos + (size_t)(row & (SEQ - 1)) * DMODEL;
  }
  float v[3];
  float s = 0.f, sq = 0.f;
#pragma unroll
  for (int j = 0; j < 3; ++j) {
    int c = tid + j * 256;
    float a;
    if (EMB) {
      a = er[c] + pr[c];
      xr[c] = a;
    } else {
      a = xr[c];
      if (RBIAS) a += rb[c];
      if (KS > 0) {
#pragma unroll
        for (int z = 0; z < KS; ++z)
          a += bf2f(part[(size_t)z * BT * DMODEL + (size_t)row * DMODEL + c]);
        xr[c] = a;
      }
    }
    v[j] = a;
    s += a;
    sq += a * a;
  }
#pragma unroll
  for (int off = 1; off < 64; off <<= 1) {
    s += __shfl_xor(s, off);
    sq += __shfl_xor(sq, off);
  }
  int wid = tid >> 6;
  if ((tid & 63) == 0) { red[wid * 2] = s; red[wid * 2 + 1] = sq; }
  __syncthreads();
  float S = red[0] + red[2] + red[4] + red[6];
  float SQ = red[1] + red[3] + red[5] + red[7];
  float mu = S * (1.0f / DMODEL);
  float var = SQ * (1.0f / DMODEL) - mu * mu;
  float r = rsqrtf(var + 1e-5f);
  ushort* orow = o + (size_t)row * DMODEL;
#pragma unroll
  for (int j = 0; j < 3; ++j) {
    int c = tid + j * 256;
    orow[c] = f2bf((v[j] - mu) * r * g[c] + bta[c]);
  }
}

// ------------------------- flash attention: dbuf K/V + counted vmcnt -------
__global__ __launch_bounds__(256) void fattn_kernel(
    const ushort* __restrict__ q, const ushort* __restrict__ k,
    const ushort* __restrict__ vt, ushort* __restrict__ o) {
  __shared__ __align__(16) ushort Ks[2][64 * 64];
  __shared__ __align__(16) ushort Vs[2][64 * 64];
  __shared__ __align__(16) ushort Ps[4][16][80];
  const int bid = blockIdx.x;
  const int wgid = (bid & 7) * 48 + (bid >> 3);
  const int z = wgid / 16, qb_ = wgid % 16;
  const int b = z / NHEAD, hh = z % NHEAD;
  const int q0 = (15 - qb_) * 64;  // long blocks first within chunk
  const int tid = threadIdx.x, w = tid >> 6, l = tid & 63;
  const int fr = l & 15, ks = l >> 4;
  const int qrow = q0 + w * 16 + fr;
  const ushort* qp = q + (size_t)(b * SEQ + qrow) * DMODEL + hh * DHEAD;
  const bf16x8 qf0 = *reinterpret_cast<const bf16x8*>(qp + ks * 8);
  const bf16x8 qf1 = *reinterpret_cast<const bf16x8*>(qp + 32 + ks * 8);

  const int srow = w * 16 + (l >> 3);
  const int g0 = ((l & 7) ^ (srow & 7)) * 8;

  auto stage = [&](int k0, int d) {
#pragma unroll
    for (int c = 0; c < 2; ++c) {
      int r = srow + c * 8;
      gl_lds16(k + (size_t)(b * SEQ + k0 + r) * DMODEL + hh * DHEAD + g0,
               &Ks[d][(w * 16 + c * 8) * 64]);
      gl_lds16(vt + (size_t)(z * 64 + r) * SEQ + k0 + g0,
               &Vs[d][(w * 16 + c * 8) * 64]);
    }
  };

  f32x4 acc_o[4] = {};
  float mrun = -1e30f, lrun = 0.f;
  const int nt = q0 >> 6;

  stage(0, 0);
  for (int t = 0; t <= nt; ++t) {
    const int cur = t & 1;
    if (t < nt) {
      stage((t + 1) * 64, cur ^ 1);
      asm volatile("s_waitcnt vmcnt(4)" ::: "memory");
    } else {
      asm volatile("s_waitcnt vmcnt(0)" ::: "memory");
    }
    __builtin_amdgcn_s_barrier();
    __builtin_amdgcn_sched_barrier(0);
    f32x4 acc_s[4] = {};
#pragma unroll
    for (int kstep = 0; kstep < 2; ++kstep) {
      const bf16x8 qf = kstep ? qf1 : qf0;
#pragma unroll
      for (int kb = 0; kb < 4; ++kb) {
        int ra = kb * 16 + fr;
        bf16x8 af = *reinterpret_cast<const bf16x8*>(
            &Ks[cur][ra * 64 + (((kstep * 4 + ks) ^ (ra & 7)) * 8)]);
        acc_s[kb] =
            __builtin_amdgcn_mfma_f32_16x16x32_bf16(af, qf, acc_s[kb], 0, 0, 0);
      }
    }
    const bool diag = (t == nt);
    float pm = -1e30f;
    float sv[4][4];
#pragma unroll
    for (int kb = 0; kb < 4; ++kb)
#pragma unroll
      for (int r = 0; r < 4; ++r) {
        float s = acc_s[kb][r];
        if (diag && (q0 + kb * 16 + ks * 4 + r > qrow)) s = -1e30f;
        sv[kb][r] = s;
        pm = fmaxf(pm, s);
      }
    pm = fmaxf(pm, __shfl_xor(pm, 16));
    pm = fmaxf(pm, __shfl_xor(pm, 32));
    if (!__all(pm - mrun <= 8.0f)) {
      float mnew = fmaxf(mrun, pm);
      float scale = __expf(mrun - mnew);
      lrun *= scale;
#pragma unroll
      for (int db = 0; db < 4; ++db) acc_o[db] *= scale;
      mrun = mnew;
    }
    float psum = 0.f;
#pragma unroll
    for (int kb = 0; kb < 4; ++kb) {
      float p0 = __expf(sv[kb][0] - mrun);
      float p1 = __expf(sv[kb][1] - mrun);
      float p2 = __expf(sv[kb][2] - mrun);
      float p3 = __expf(sv[kb][3] - mrun);
      psum += (p0 + p1) + (p2 + p3);
      *reinterpret_cast<ushort4*>(&Ps[w][fr][kb * 16 + ks * 4]) =
          make_ushort4(f2bf(p0), f2bf(p1), f2bf(p2), f2bf(p3));
    }
    psum += __shfl_xor(psum, 16);
    psum += __shfl_xor(psum, 32);
    lrun += psum;
#pragma unroll
    for (int kstep = 0; kstep < 2; ++kstep) {
      bf16x8 pf =
          *reinterpret_cast<const bf16x8*>(&Ps[w][fr][kstep * 32 + ks * 8]);
#pragma unroll
      for (int db = 0; db < 4; ++db) {
        int rd = db * 16 + fr;
        bf16x8 vf = *reinterpret_cast<const bf16x8*>(
            &Vs[cur][rd * 64 + (((kstep * 4 + ks) ^ (rd & 7)) * 8)]);
        acc_o[db] =
            __builtin_amdgcn_mfma_f32_16x16x32_bf16(vf, pf, acc_o[db], 0, 0, 0);
      }
    }
    __builtin_amdgcn_sched_barrier(0);
    __builtin_amdgcn_s_barrier();
  }
  float rinv = 1.0f / lrun;
#pragma unroll
  for (int db = 0; db < 4; ++db) {
    ushort4 o4 =
        make_ushort4(f2bf(acc_o[db][0] * rinv), f2bf(acc_o[db][1] * rinv),
                     f2bf(acc_o[db][2] * rinv), f2bf(acc_o[db][3] * rinv));
    *reinterpret_cast<ushort4*>(o + (size_t)(b * SEQ + qrow) * DMODEL +
                                hh * DHEAD + db * 16 + ks * 4) = o4;
  }
}

// ------------------------------------------------------- bf16 MFMA NT GEMM
// 128x128 tile, BK=32, 2-deep ring, counted vmcnt. Layer GEMMs.
template <bool QKV, bool BIAS, bool GELU, bool RES, bool OUTBF, bool SWZ,
          bool PART>
__global__ __launch_bounds__(256) void gemm_bf16_nt(
    const ushort* __restrict__ A, const ushort* __restrict__ B,
    const float* __restrict__ bias, const int* __restrict__ tmask,
    const float* __restrict__ res, float* __restrict__ Cf,
    ushort* __restrict__ Cb, int ldc, ushort* __restrict__ qb,
    ushort* __restrict__ kb, ushort* __restrict__ vt, int M, int K, int Nreal,
    int kchunk) {
  __shared__ __align__(16) ushort As[2][128 * 32];
  __shared__ __align__(16) ushort Bs[2][128 * 32];
  int bnx, bmy;
  if (SWZ) {
    int bid = blockIdx.x;
    int chunk = gridDim.x >> 3;
    int wgid = (bid & 7) * chunk + (bid >> 3);
    int mb = M >> 7;
    bmy = wgid % mb;
    bnx = wgid / mb;
  } else {
    bnx = blockIdx.x;
    bmy = blockIdx.y;
  }
  const int m0 = bmy * 128, n0 = bnx * 128;
  const int kbeg = PART ? blockIdx.z * kchunk : 0;
  const int kend = PART ? kbeg + kchunk : K;
  if (PART) Cb += (size_t)blockIdx.z * M * ldc;
  const int tid = threadIdx.x;
  const int w = tid >> 6, l = tid & 63;
  const int wr = w >> 1, wc = w & 1;
  const int fr = l & 15, ks = l >> 4;

  const int seg0 = w * 2, seg1 = w * 2 + 1;
  const int srow0 = seg0 * 16 + (l >> 2);
  const int srow1 = seg1 * 16 + (l >> 2);
  const int koff0 = (((l & 3) ^ ((srow0 >> 1) & 3))) * 8;
  const int koff1 = (((l & 3) ^ ((srow1 >> 1) & 3))) * 8;
  const ushort* A0 = A + (size_t)(m0 + srow0) * K + koff0;
  const ushort* A1 = A + (size_t)(m0 + srow1) * K + koff1;
  const ushort* B0 = B + (size_t)(n0 + srow0) * K + koff0;
  const ushort* B1 = B + (size_t)(n0 + srow1) * K + koff1;

  int aoff[4], boff[4];
#pragma unroll
  for (int i = 0; i < 4; ++i) {
    int ra = wr * 64 + i * 16 + fr;
    aoff[i] = ra * 32 + ((ks ^ ((ra >> 1) & 3)) * 8);
    int rb = wc * 64 + i * 16 + fr;
    boff[i] = rb * 32 + ((ks ^ ((rb >> 1) & 3)) * 8);
  }

  gl_lds16(A0 + kbeg, &As[0][seg0 * 512]);
  gl_lds16(A1 + kbeg, &As[0][seg1 * 512]);
  gl_lds16(B0 + kbeg, &Bs[0][seg0 * 512]);
  gl_lds16(B1 + kbeg, &Bs[0][seg1 * 512]);

  f32x4 acc[4][4] = {};
  int cur = 0;
  for (int k0 = kbeg; k0 < kend; k0 += 32) {
    const int nxt = k0 + 32;
    if (nxt < kend) {
      gl_lds16(A0 + nxt, &As[cur ^ 1][seg0 * 512]);
      gl_lds16(A1 + nxt, &As[cur ^ 1][seg1 * 512]);
      gl_lds16(B0 + nxt, &Bs[cur ^ 1][seg0 * 512]);
      gl_lds16(B1 + nxt, &Bs[cur ^ 1][seg1 * 512]);
      asm volatile("s_waitcnt vmcnt(4)" ::: "memory");
    } else {
      asm volatile("s_waitcnt vmcnt(0)" ::: "memory");
    }
    __builtin_amdgcn_s_barrier();
    __builtin_amdgcn_sched_barrier(0);
    bf16x8 af[4], bfr[4];
#pragma unroll
    for (int i = 0; i < 4; ++i)
      af[i] = *reinterpret_cast<const bf16x8*>(&As[cur][aoff[i]]);
#pragma unroll
    for (int i = 0; i < 4; ++i)
      bfr[i] = *reinterpret_cast<const bf16x8*>(&Bs[cur][boff[i]]);
#pragma unroll
    for (int mi = 0; mi < 4; ++mi)
#pragma unroll
      for (int nj = 0; nj < 4; ++nj)
        acc[mi][nj] = __builtin_amdgcn_mfma_f32_16x16x32_bf16(
            af[mi], bfr[nj], acc[mi][nj], 0, 0, 0);
    __builtin_amdgcn_sched_barrier(0);
    __builtin_amdgcn_s_barrier();
    cur ^= 1;
  }

#pragma unroll
  for (int mi = 0; mi < 4; ++mi) {
#pragma unroll
    for (int nj = 0; nj < 4; ++nj) {
      int n = n0 + wc * 64 + nj * 16 + fr;
      if (n < Nreal) {
        if (PART) {
#pragma unroll
          for (int r = 0; r < 4; ++r) {
            int m = m0 + wr * 64 + mi * 16 + ks * 4 + r;
            Cb[(size_t)m * ldc + n] = f2bf(acc[mi][nj][r]);
          }
        } else if (QKV) {
          if (n < DMODEL) {
            float sc = (1.0f - 0.5f * (float)tmask[n]) * 0.125f;
#pragma unroll
            for (int r = 0; r < 4; ++r) {
              int m = m0 + wr * 64 + mi * 16 + ks * 4 + r;
              qb[(size_t)m * DMODEL + n] = f2bf(acc[mi][nj][r] * sc);
            }
          } else if (n < 2 * DMODEL) {
#pragma unroll
            for (int r = 0; r < 4; ++r) {
              int m = m0 + wr * 64 + mi * 16 + ks * 4 + r;
              kb[(size_t)m * DMODEL + (n - DMODEL)] = f2bf(acc[mi][nj][r]);
            }
          } else {
            int d = n - 2 * DMODEL;
            int key = (m0 & (SEQ - 1)) + wr * 64 + mi * 16 + ks * 4;
            size_t zr = (size_t)((m0 >> 10) * NHEAD + (d >> 6)) * 64 + (d & 63);
            ushort4 p4 = make_ushort4(
                f2bf(acc[mi][nj][0]), f2bf(acc[mi][nj][1]),
                f2bf(acc[mi][nj][2]), f2bf(acc[mi][nj][3]));
            *reinterpret_cast<ushort4*>(vt + zr * SEQ + key) = p4;
          }
        } else {
#pragma unroll
          for (int r = 0; r < 4; ++r) {
            int m = m0 + wr * 64 + mi * 16 + ks * 4 + r;
            float v = acc[mi][nj][r];
            if (BIAS) v += bias[n];
            if (GELU) v = 0.5f * v * (1.0f + erff(v * 0.70710678118f));
            if (RES) v += res[(size_t)m * ldc + n];
            if (OUTBF)
              Cb[(size_t)m * ldc + n] = f2bf(v);
            else
              Cf[(size_t)m * ldc + n] = v;
          }
        }
      }
    }
  }
}

// ---------------- LM head: 256x256, BK=64, 8-phase, coalesced epilogue ----
__global__ __launch_bounds__(512, 2) void gemm_lmhead(
    const ushort* __restrict__ A, const ushort* __restrict__ B,
    float* __restrict__ C) {
  __shared__ __align__(16) ushort SMEM[4 * 256 * 64];  // 128 KB
  const int K = DMODEL;      // 768
  const int NTILE = K / 64;  // 12
  const int ITERS = NTILE / 2;

  const int bid = blockIdx.x;
  const int chunk = gridDim.x >> 3;  // 197
  const int wgid = (bid & 7) * chunk + (bid >> 3);
  const int m0 = (wgid & 7) * 256;   // m fast -> B-panel reuse within XCD
  const int n0 = (wgid >> 3) * 256;

  const int tid = threadIdx.x;
  const int w = tid >> 6, l = tid & 63;
  const int wr = w >> 2, wc = w & 3;
  const int fr = l & 15, ks = l >> 4;

  const int strow = tid >> 3;                   // 0..63
  const int stk = ((tid & 7) ^ (strow & 7)) * 8;
  const int wseg = (w << 3) * 64;               // wave's 8-row LDS segment

  const int fsw0 = (ks ^ (fr & 7)) * 8;
  const int fsw1 = ((4 | ks) ^ (fr & 7)) * 8;
  const int arow = (wr * 128 + fr) * 64;  // + mi*16*64
  const int brow = (wc * 64 + fr) * 64;   // + nj*16*64

  bf16x8 Ar[4][2], Br[4][2];
  f32x4 acc[8][4] = {};

#define STA(d, kt, rb)                                            \
  gl_lds16(A + (size_t)(m0 + (rb) + strow) * K + (kt) * 64 + stk, \
           SMEM + (d) * 16384 + (rb) * 64 + wseg)
#define STB(d, kt, rb)                                            \
  gl_lds16(B + (size_t)(n0 + (rb) + strow) * K + (kt) * 64 + stk, \
           SMEM + 32768 + (d) * 16384 + (rb) * 64 + wseg)
#define RDA(d, mi, kst)                           \
  (*reinterpret_cast<const bf16x8*>(              \
      &SMEM[(d) * 16384 + arow + (mi) * 1024 + ((kst) ? fsw1 : fsw0)]))
#define RDB(d, nj, kst)                           \
  (*reinterpret_cast<const bf16x8*>(              \
      &SMEM[32768 + (d) * 16384 + brow + (nj) * 1024 + ((kst) ? fsw1 : fsw0)]))
#define MMAQ(mh, nh)                                                       \
  _Pragma("unroll") for (int kst = 0; kst < 2; ++kst)                      \
  _Pragma("unroll") for (int mi = 0; mi < 4; ++mi)                         \
  _Pragma("unroll") for (int nj = 0; nj < 2; ++nj)                         \
    acc[(mh)*4 + mi][(nh)*2 + nj] = __builtin_amdgcn_mfma_f32_16x16x32_bf16( \
        Ar[mi][kst], Br[(nh)*2 + nj][kst], acc[(mh)*4 + mi][(nh)*2 + nj],  \
        0, 0, 0)
#define BAR __builtin_amdgcn_s_barrier()
#define PRIO1 __builtin_amdgcn_s_setprio(1)
#define PRIO0 __builtin_amdgcn_s_setprio(0)

  STA(0, 0, 0); STA(0, 0, 64); STA(0, 0, 128); STA(0, 0, 192);
  STB(0, 0, 0); STB(0, 0, 64); STB(0, 0, 128); STB(0, 0, 192);
  STB(1, 1, 0); STB(1, 1, 64); STB(1, 1, 128); STB(1, 1, 192);
  asm volatile("s_waitcnt vmcnt(4)" ::: "memory");
  BAR;

  for (int it = 0; it < ITERS; ++it) {
    const int t1 = 2 * it + 1;
    const int tn = 2 * it + 2;
    const bool s0 = tn < NTILE, s1 = tn + 1 < NTILE;
#pragma unroll
    for (int mi = 0; mi < 4; ++mi) {
      Ar[mi][0] = RDA(0, mi, 0); Ar[mi][1] = RDA(0, mi, 1);
    }
#pragma unroll
    for (int nj = 0; nj < 2; ++nj) {
      Br[nj][0] = RDB(0, nj, 0); Br[nj][1] = RDB(0, nj, 1);
    }
    STA(1, t1, 0); STA(1, t1, 64);
    BAR; PRIO1; MMAQ(0, 0); PRIO0; BAR;
#pragma unroll
    for (int nj = 2; nj < 4; ++nj) {
      Br[nj][0] = RDB(0, nj, 0); Br[nj][1] = RDB(0, nj, 1);
    }
    STA(1, t1, 128); STA(1, t1, 192);
    BAR; PRIO1; MMAQ(0, 1); PRIO0; BAR;
#pragma unroll
    for (int mi = 0; mi < 4; ++mi) {
      Ar[mi][0] = RDA(0, mi + 4, 0); Ar[mi][1] = RDA(0, mi + 4, 1);
    }
    if (s0) { STB(0, tn, 0); STB(0, tn, 64); }
    BAR; PRIO1; MMAQ(1, 1); PRIO0; BAR;
    if (s0) { STB(0, tn, 128); STB(0, tn, 192); }
    BAR; PRIO1; MMAQ(1, 0); PRIO0;
    if (s0)
      asm volatile("s_waitcnt vmcnt(4)" ::: "memory");
    else
      asm volatile("s_waitcnt vmcnt(0)" ::: "memory");
    BAR;
#pragma unroll
    for (int mi = 0; mi < 4; ++mi) {
      Ar[mi][0] = RDA(1, mi, 0); Ar[mi][1] = RDA(1, mi, 1);
    }
#pragma unroll
    for (int nj = 0; nj < 2; ++nj) {
      Br[nj][0] = RDB(1, nj, 0); Br[nj][1] = RDB(1, nj, 1);
    }
    if (s0) { STA(0, tn, 0); STA(0, tn, 64); }
    BAR; PRIO1; MMAQ(0, 0); PRIO0; BAR;
#pragma unroll
    for (int nj = 2; nj < 4; ++nj) {
      Br[nj][0] = RDB(1, nj, 0); Br[nj][1] = RDB(1, nj, 1);
    }
    if (s0) { STA(0, tn, 128); STA(0, tn, 192); }
    BAR; PRIO1; MMAQ(0, 1); PRIO0; BAR;
#pragma unroll
    for (int mi = 0; mi < 4; ++mi) {
      Ar[mi][0] = RDA(1, mi + 4, 0); Ar[mi][1] = RDA(1, mi + 4, 1);
    }
    if (s1) { STB(1, tn + 1, 0); STB(1, tn + 1, 64); }
    BAR; PRIO1; MMAQ(1, 1); PRIO0; BAR;
    if (s1) { STB(1, tn + 1, 128); STB(1, tn + 1, 192); }
    BAR; PRIO1; MMAQ(1, 0); PRIO0;
    if (it + 1 < ITERS) {
      asm volatile("s_waitcnt vmcnt(4)" ::: "memory");
      BAR;
    }
  }

  // ---- coalesced epilogue: two 128-row halves through LDS ----
  float* eb = reinterpret_cast<float*>(SMEM);  // [128][256] fp32
#pragma unroll 1
  for (int p = 0; p < 2; ++p) {
    __syncthreads();
    if (wr == p) {
#pragma unroll
      for (int mi = 0; mi < 8; ++mi)
#pragma unroll
        for (int nj = 0; nj < 4; ++nj)
#pragma unroll
          for (int r = 0; r < 4; ++r)
            eb[(mi * 16 + ks * 4 + r) * 256 + wc * 64 + nj * 16 + fr] =
                acc[mi][nj][r];
    }
    __syncthreads();
    const size_t rowbase = (size_t)(m0 + p * 128) * VOCABSZ + n0;
#pragma unroll 8
    for (int c = 0; c < 64; ++c) {
      int lin = c * 512 + tid;
      int row = lin >> 8, col = lin & 255;
      if (n0 + col < VOCABSZ) {
        __builtin_nontemporal_store(
            eb[lin], C + rowbase + (size_t)row * VOCABSZ + col);
      }
    }
  }
#undef STA
#undef STB
#undef RDA
#undef RDB
#undef MMAQ
#undef BAR
#undef PRIO1
#undef PRIO0
}

// ---------------------------------------------------------------- launch
extern "C" void kernel_launch(void* const* d_in, const int* in_sizes, int n_in,
                              void* d_out, int out_size, void* d_ws,
                              size_t ws_size, hipStream_t stream) {
  const int* tokens = (const int*)d_in[0];
  const int* tmask = (const int*)d_in[1];
  const float* embed = (const float*)d_in[2];
  const float* pos = (const float*)d_in[3];
  const float* wq = (const float*)d_in[4];
  const float* wk = (const float*)d_in[5];
  const float* wv = (const float*)d_in[6];
  const float* wo = (const float*)d_in[7];
  const float* ln1g = (const float*)d_in[8];
  const float* ln1b = (const float*)d_in[9];
  const float* ln2g = (const float*)d_in[10];
  const float* ln2b = (const float*)d_in[11];
  const float* fw1 = (const float*)d_in[12];
  const float* fb1 = (const float*)d_in[13];
  const float* fw2 = (const float*)d_in[14];
  const float* fb2 = (const float*)d_in[15];
  const float* lnfg = (const float*)d_in[16];
  const float* lnfb = (const float*)d_in[17];

  char* wp = (char*)d_ws;
  auto alloc = [&](size_t bytes) {
    void* p = wp;
    wp += (bytes + 255) & ~(size_t)255;
    return p;
  };
  float* h = (float*)alloc((size_t)BT * DMODEL * 4);
  ushort* part = (ushort*)alloc((size_t)2 * BT * DMODEL * 2);
  ushort* qb = (ushort*)alloc((size_t)BT * DMODEL * 2);
  ushort* kb = (ushort*)alloc((size_t)BT * DMODEL * 2);
  ushort* vt = (ushort*)alloc((size_t)NBH * DHEAD * SEQ * 2);
  ushort* xn = (ushort*)alloc((size_t)BT * DMODEL * 2);
  ushort* ab = (ushort*)alloc((size_t)BT * DMODEL * 2);
  ushort* ffb = (ushort*)alloc((size_t)BT * DFFN * 2);
  ushort* wqkv_b = (ushort*)alloc((size_t)NLAYER * 3 * DMODEL * DMODEL * 2);
  ushort* wo_b = (ushort*)alloc((size_t)NLAYER * DMODEL * DMODEL * 2);
  ushort* fw1_b = (ushort*)alloc((size_t)NLAYER * DFFN * DMODEL * 2);
  ushort* fw2_b = (ushort*)alloc((size_t)NLAYER * DMODEL * DFFN * 2);
  ushort* emb_b = (ushort*)alloc((size_t)VPAD * DMODEL * 2);

  const int per4 = DMODEL * DMODEL / 4;
  const int nff4 = NLAYER * DFFN * DMODEL / 4;
  conv_qkv3_kernel<<<(3 * NLAYER * per4 + 255) / 256, 256, 0, stream>>>(
      wq, wk, wv, wqkv_b);
  conv3_kernel<<<(NLAYER * per4 + 2 * nff4 + 255) / 256, 256, 0, stream>>>(
      wo, wo_b, fw1, fw1_b, fw2, fw2_b);
  conv_embed_kernel<<<(VPAD * DMODEL / 4 + 255) / 256, 256, 0, stream>>>(
      embed, emb_b);

  const dim3 gqkv(3 * DMODEL / 128, BT / 128);
  const dim3 gff(DFFN / 128, BT / 128);
  const dim3 gwo(DMODEL / 128, BT / 128, 2);
  const dim3 gff2(DMODEL / 128, BT / 128, 2);

  for (int i = 0; i < NLAYER; ++i) {
    if (i == 0)
      ln_kernel<0, false, true><<<BT, 256, 0, stream>>>(
          h, nullptr, nullptr, tokens, embed, pos, ln1g, ln1b, xn);
    else
      ln_kernel<2, true, false><<<BT, 256, 0, stream>>>(
          h, part, fb2 + (i - 1) * DMODEL, nullptr, nullptr, nullptr,
          ln1g + i * DMODEL, ln1b + i * DMODEL, xn);

    gemm_bf16_nt<true, false, false, false, false, false, false>
        <<<gqkv, 256, 0, stream>>>(
            xn, wqkv_b + (size_t)i * 3 * DMODEL * DMODEL, nullptr,
            tmask + i * DMODEL, nullptr, nullptr, nullptr, 0, qb, kb, vt, BT,
            DMODEL, 3 * DMODEL, DMODEL);

    fattn_kernel<<<NBH * (SEQ / 64), 256, 0, stream>>>(qb, kb, vt, ab);

    gemm_bf16_nt<false, false, false, false, false, false, true>
        <<<gwo, 256, 0, stream>>>(
            ab, wo_b + (size_t)i * DMODEL * DMODEL, nullptr, nullptr, nullptr,
            nullptr, part, DMODEL, nullptr, nullptr, nullptr, BT, DMODEL,
            DMODEL, DMODEL / 2);

    ln_kernel<2, false, false><<<BT, 256, 0, stream>>>(
        h, part, nullptr, nullptr, nullptr, nullptr, ln2g + i * DMODEL,
        ln2b + i * DMODEL, xn);

    gemm_bf16_nt<false, true, true, false, true, false, false>
        <<<gff, 256, 0, stream>>>(
            xn, fw1_b + (size_t)i * DFFN * DMODEL, fb1 + i * DFFN, nullptr,
            nullptr, nullptr, ffb, DFFN, nullptr, nullptr, nullptr, BT, DMODEL,
            DFFN, DMODEL);

    gemm_bf16_nt<false, false, false, false, false, false, true>
        <<<gff2, 256, 0, stream>>>(
            ffb, fw2_b + (size_t)i * DMODEL * DFFN, nullptr, nullptr, nullptr,
            nullptr, part, DMODEL, nullptr, nullptr, nullptr, BT, DFFN, DMODEL,
            DFFN / 2);
  }

  ln_kernel<2, true, false><<<BT, 256, 0, stream>>>(
      h, part, fb2 + (NLAYER - 1) * DMODEL, nullptr, nullptr, nullptr, lnfg,
      lnfb, xn);

  gemm_lmhead<<<8 * (VPAD / 256), 512, 0, stream>>>(xn, emb_b, (float*)d_out);
}

// Round 15
// 839.664 us; speedup vs baseline: 1.0659x; 1.0659x over previous
//
#include <hip/hip_runtime.h>
#include <math.h>

#define VOCABSZ 50257
#define VPAD 50432
#define DMODEL 768
#define NHEAD 12
#define NLAYER 4
#define SEQ 1024
#define BATCH 2
#define DHEAD 64
#define DFFN 3072
#define BT (BATCH * SEQ)
#define NBH (BATCH * NHEAD)

typedef __attribute__((ext_vector_type(8))) short bf16x8;
typedef __attribute__((ext_vector_type(4))) float f32x4;

__device__ __forceinline__ ushort f2bf(float f) {
  uint u = __builtin_bit_cast(uint, f);
  u = (u + 0x7fffu + ((u >> 16) & 1u)) >> 16;
  return (ushort)u;
}

__device__ __forceinline__ float bf2f(ushort u) {
  uint x = ((uint)u) << 16;
  return __builtin_bit_cast(float, x);
}

__device__ __forceinline__ void gl_lds16(const ushort* g, ushort* l) {
  __builtin_amdgcn_global_load_lds(
      (const __attribute__((address_space(1))) void*)g,
      (__attribute__((address_space(3))) void*)l, 16, 0, 0);
}

// ------------------------------------------------------------- conversions
__global__ __launch_bounds__(256) void conv_qkv3_kernel(
    const float* __restrict__ wq, const float* __restrict__ wk,
    const float* __restrict__ wv, ushort* __restrict__ dst) {
  const int per4 = DMODEL * DMODEL / 4;
  const int total = NLAYER * per4;
  int i = blockIdx.x * 256 + threadIdx.x;
  if (i >= 3 * total) return;
  int which = i / total;
  int rem = i - which * total;
  const float* src = (which == 0) ? wq : (which == 1) ? wk : wv;
  int layer = rem / per4, r2 = rem % per4;
  float4 v = reinterpret_cast<const float4*>(src)[rem];
  reinterpret_cast<ushort4*>(dst)[(size_t)layer * (3 * per4) + which * per4 +
                                  r2] =
      make_ushort4(f2bf(v.x), f2bf(v.y), f2bf(v.z), f2bf(v.w));
}

__global__ __launch_bounds__(256) void conv3_kernel(
    const float* __restrict__ wo, ushort* __restrict__ wo_b,
    const float* __restrict__ fw1, ushort* __restrict__ fw1_b,
    const float* __restrict__ fw2, ushort* __restrict__ fw2_b) {
  const int n1 = NLAYER * DMODEL * DMODEL / 4;
  const int nf = NLAYER * DFFN * DMODEL / 4;
  int i = blockIdx.x * 256 + threadIdx.x;
  const float* src;
  ushort* dst;
  int idx;
  if (i < n1) {
    src = wo; dst = wo_b; idx = i;
  } else if (i < n1 + nf) {
    src = fw1; dst = fw1_b; idx = i - n1;
  } else if (i < n1 + 2 * nf) {
    src = fw2; dst = fw2_b; idx = i - n1 - nf;
  } else {
    return;
  }
  float4 v = reinterpret_cast<const float4*>(src)[idx];
  reinterpret_cast<ushort4*>(dst)[idx] =
      make_ushort4(f2bf(v.x), f2bf(v.y), f2bf(v.z), f2bf(v.w));
}

__global__ __launch_bounds__(256) void conv_embed_kernel(
    const float* __restrict__ emb, ushort* __restrict__ dst) {
  int i = blockIdx.x * 256 + threadIdx.x;
  if (i >= VPAD * DMODEL / 4) return;
  int row = (i * 4) / DMODEL;
  ushort4 o = make_ushort4(0, 0, 0, 0);
  if (row < VOCABSZ) {
    float4 v = reinterpret_cast<const float4*>(emb)[i];
    o = make_ushort4(f2bf(v.x), f2bf(v.y), f2bf(v.z), f2bf(v.w));
  }
  reinterpret_cast<ushort4*>(dst)[i] = o;
}

// --------------- layernorm (+ fused split-K reduce / embedding, bf16 parts)
template <int KS, bool RBIAS, bool EMB>
__global__ __launch_bounds__(256) void ln_kernel(
    float* __restrict__ h, const ushort* __restrict__ part,
    const float* __restrict__ rb, const int* __restrict__ tok,
    const float* __restrict__ emb, const float* __restrict__ pos,
    const float* __restrict__ g, const float* __restrict__ bta,
    ushort* __restrict__ o) {
  __shared__ float red[8];
  int row = blockIdx.x;
  int tid = threadIdx.x;
  float* xr = h + (size_t)row * DMODEL;
  const float* er = nullptr;
  const float* pr = nullptr;
  if (EMB) {
    er = emb + (size_t)tok[row] * DMODEL;
    pr = pos + (size_t)(row & (SEQ - 1)) * DMODEL;
  }
  float v[3];
  float s = 0.f, sq = 0.f;
#pragma unroll
  for (int j = 0; j < 3; ++j) {
    int c = tid + j * 256;
    float a;
    if (EMB) {
      a = er[c] + pr[c];
      xr[c] = a;
    } else {
      a = xr[c];
      if (RBIAS) a += rb[c];
      if (KS > 0) {
#pragma unroll
        for (int z = 0; z < KS; ++z)
          a += bf2f(part[(size_t)z * BT * DMODEL + (size_t)row * DMODEL + c]);
        xr[c] = a;
      }
    }
    v[j] = a;
    s += a;
    sq += a * a;
  }
#pragma unroll
  for (int off = 1; off < 64; off <<= 1) {
    s += __shfl_xor(s, off);
    sq += __shfl_xor(sq, off);
  }
  int wid = tid >> 6;
  if ((tid & 63) == 0) { red[wid * 2] = s; red[wid * 2 + 1] = sq; }
  __syncthreads();
  float S = red[0] + red[2] + red[4] + red[6];
  float SQ = red[1] + red[3] + red[5] + red[7];
  float mu = S * (1.0f / DMODEL);
  float var = SQ * (1.0f / DMODEL) - mu * mu;
  float r = rsqrtf(var + 1e-5f);
  ushort* orow = o + (size_t)row * DMODEL;
#pragma unroll
  for (int j = 0; j < 3; ++j) {
    int c = tid + j * 256;
    orow[c] = f2bf((v[j] - mu) * r * g[c] + bta[c]);
  }
}

// ------------------------- flash attention: dbuf K/V + counted vmcnt -------
__global__ __launch_bounds__(256) void fattn_kernel(
    const ushort* __restrict__ q, const ushort* __restrict__ k,
    const ushort* __restrict__ vt, ushort* __restrict__ o) {
  __shared__ __align__(16) ushort Ks[2][64 * 64];
  __shared__ __align__(16) ushort Vs[2][64 * 64];
  __shared__ __align__(16) ushort Ps[4][16][80];
  const int bid = blockIdx.x;
  const int wgid = (bid & 7) * 48 + (bid >> 3);
  const int z = wgid / 16, qb_ = wgid % 16;
  const int b = z / NHEAD, hh = z % NHEAD;
  const int q0 = (15 - qb_) * 64;  // long blocks first within chunk
  const int tid = threadIdx.x, w = tid >> 6, l = tid & 63;
  const int fr = l & 15, ks = l >> 4;
  const int qrow = q0 + w * 16 + fr;
  const ushort* qp = q + (size_t)(b * SEQ + qrow) * DMODEL + hh * DHEAD;
  const bf16x8 qf0 = *reinterpret_cast<const bf16x8*>(qp + ks * 8);
  const bf16x8 qf1 = *reinterpret_cast<const bf16x8*>(qp + 32 + ks * 8);

  const int srow = w * 16 + (l >> 3);
  const int g0 = ((l & 7) ^ (srow & 7)) * 8;

  auto stage = [&](int k0, int d) {
#pragma unroll
    for (int c = 0; c < 2; ++c) {
      int r = srow + c * 8;
      gl_lds16(k + (size_t)(b * SEQ + k0 + r) * DMODEL + hh * DHEAD + g0,
               &Ks[d][(w * 16 + c * 8) * 64]);
      gl_lds16(vt + (size_t)(z * 64 + r) * SEQ + k0 + g0,
               &Vs[d][(w * 16 + c * 8) * 64]);
    }
  };

  f32x4 acc_o[4] = {};
  float mrun = -1e30f, lrun = 0.f;
  const int nt = q0 >> 6;

  stage(0, 0);
  for (int t = 0; t <= nt; ++t) {
    const int cur = t & 1;
    if (t < nt) {
      stage((t + 1) * 64, cur ^ 1);
      asm volatile("s_waitcnt vmcnt(4)" ::: "memory");
    } else {
      asm volatile("s_waitcnt vmcnt(0)" ::: "memory");
    }
    __builtin_amdgcn_s_barrier();
    __builtin_amdgcn_sched_barrier(0);
    f32x4 acc_s[4] = {};
#pragma unroll
    for (int kstep = 0; kstep < 2; ++kstep) {
      const bf16x8 qf = kstep ? qf1 : qf0;
#pragma unroll
      for (int kb = 0; kb < 4; ++kb) {
        int ra = kb * 16 + fr;
        bf16x8 af = *reinterpret_cast<const bf16x8*>(
            &Ks[cur][ra * 64 + (((kstep * 4 + ks) ^ (ra & 7)) * 8)]);
        acc_s[kb] =
            __builtin_amdgcn_mfma_f32_16x16x32_bf16(af, qf, acc_s[kb], 0, 0, 0);
      }
    }
    const bool diag = (t == nt);
    float pm = -1e30f;
    float sv[4][4];
#pragma unroll
    for (int kb = 0; kb < 4; ++kb)
#pragma unroll
      for (int r = 0; r < 4; ++r) {
        float s = acc_s[kb][r];
        if (diag && (q0 + kb * 16 + ks * 4 + r > qrow)) s = -1e30f;
        sv[kb][r] = s;
        pm = fmaxf(pm, s);
      }
    pm = fmaxf(pm, __shfl_xor(pm, 16));
    pm = fmaxf(pm, __shfl_xor(pm, 32));
    if (!__all(pm - mrun <= 8.0f)) {
      float mnew = fmaxf(mrun, pm);
      float scale = __expf(mrun - mnew);
      lrun *= scale;
#pragma unroll
      for (int db = 0; db < 4; ++db) acc_o[db] *= scale;
      mrun = mnew;
    }
    float psum = 0.f;
#pragma unroll
    for (int kb = 0; kb < 4; ++kb) {
      float p0 = __expf(sv[kb][0] - mrun);
      float p1 = __expf(sv[kb][1] - mrun);
      float p2 = __expf(sv[kb][2] - mrun);
      float p3 = __expf(sv[kb][3] - mrun);
      psum += (p0 + p1) + (p2 + p3);
      *reinterpret_cast<ushort4*>(&Ps[w][fr][kb * 16 + ks * 4]) =
          make_ushort4(f2bf(p0), f2bf(p1), f2bf(p2), f2bf(p3));
    }
    psum += __shfl_xor(psum, 16);
    psum += __shfl_xor(psum, 32);
    lrun += psum;
#pragma unroll
    for (int kstep = 0; kstep < 2; ++kstep) {
      bf16x8 pf =
          *reinterpret_cast<const bf16x8*>(&Ps[w][fr][kstep * 32 + ks * 8]);
#pragma unroll
      for (int db = 0; db < 4; ++db) {
        int rd = db * 16 + fr;
        bf16x8 vf = *reinterpret_cast<const bf16x8*>(
            &Vs[cur][rd * 64 + (((kstep * 4 + ks) ^ (rd & 7)) * 8)]);
        acc_o[db] =
            __builtin_amdgcn_mfma_f32_16x16x32_bf16(vf, pf, acc_o[db], 0, 0, 0);
      }
    }
    __builtin_amdgcn_sched_barrier(0);
    __builtin_amdgcn_s_barrier();
  }
  float rinv = 1.0f / lrun;
#pragma unroll
  for (int db = 0; db < 4; ++db) {
    ushort4 o4 =
        make_ushort4(f2bf(acc_o[db][0] * rinv), f2bf(acc_o[db][1] * rinv),
                     f2bf(acc_o[db][2] * rinv), f2bf(acc_o[db][3] * rinv));
    *reinterpret_cast<ushort4*>(o + (size_t)(b * SEQ + qrow) * DMODEL +
                                hh * DHEAD + db * 16 + ks * 4) = o4;
  }
}

// ------------------------------------------------------- bf16 MFMA NT GEMM
// 128x128 tile, BK=32, 2-deep ring, counted vmcnt. Layer GEMMs.
template <bool QKV, bool BIAS, bool GELU, bool RES, bool OUTBF, bool SWZ,
          bool PART>
__global__ __launch_bounds__(256) void gemm_bf16_nt(
    const ushort* __restrict__ A, const ushort* __restrict__ B,
    const float* __restrict__ bias, const int* __restrict__ tmask,
    const float* __restrict__ res, float* __restrict__ Cf,
    ushort* __restrict__ Cb, int ldc, ushort* __restrict__ qb,
    ushort* __restrict__ kb, ushort* __restrict__ vt, int M, int K, int Nreal,
    int kchunk) {
  __shared__ __align__(16) ushort As[2][128 * 32];
  __shared__ __align__(16) ushort Bs[2][128 * 32];
  int bnx, bmy;
  if (SWZ) {
    int bid = blockIdx.x;
    int chunk = gridDim.x >> 3;
    int wgid = (bid & 7) * chunk + (bid >> 3);
    int mb = M >> 7;
    bmy = wgid % mb;
    bnx = wgid / mb;
  } else {
    bnx = blockIdx.x;
    bmy = blockIdx.y;
  }
  const int m0 = bmy * 128, n0 = bnx * 128;
  const int kbeg = PART ? blockIdx.z * kchunk : 0;
  const int kend = PART ? kbeg + kchunk : K;
  if (PART) Cb += (size_t)blockIdx.z * M * ldc;
  const int tid = threadIdx.x;
  const int w = tid >> 6, l = tid & 63;
  const int wr = w >> 1, wc = w & 1;
  const int fr = l & 15, ks = l >> 4;

  const int seg0 = w * 2, seg1 = w * 2 + 1;
  const int srow0 = seg0 * 16 + (l >> 2);
  const int srow1 = seg1 * 16 + (l >> 2);
  const int koff0 = (((l & 3) ^ ((srow0 >> 1) & 3))) * 8;
  const int koff1 = (((l & 3) ^ ((srow1 >> 1) & 3))) * 8;
  const ushort* A0 = A + (size_t)(m0 + srow0) * K + koff0;
  const ushort* A1 = A + (size_t)(m0 + srow1) * K + koff1;
  const ushort* B0 = B + (size_t)(n0 + srow0) * K + koff0;
  const ushort* B1 = B + (size_t)(n0 + srow1) * K + koff1;

  int aoff[4], boff[4];
#pragma unroll
  for (int i = 0; i < 4; ++i) {
    int ra = wr * 64 + i * 16 + fr;
    aoff[i] = ra * 32 + ((ks ^ ((ra >> 1) & 3)) * 8);
    int rb = wc * 64 + i * 16 + fr;
    boff[i] = rb * 32 + ((ks ^ ((rb >> 1) & 3)) * 8);
  }

  gl_lds16(A0 + kbeg, &As[0][seg0 * 512]);
  gl_lds16(A1 + kbeg, &As[0][seg1 * 512]);
  gl_lds16(B0 + kbeg, &Bs[0][seg0 * 512]);
  gl_lds16(B1 + kbeg, &Bs[0][seg1 * 512]);

  f32x4 acc[4][4] = {};
  int cur = 0;
  for (int k0 = kbeg; k0 < kend; k0 += 32) {
    const int nxt = k0 + 32;
    if (nxt < kend) {
      gl_lds16(A0 + nxt, &As[cur ^ 1][seg0 * 512]);
      gl_lds16(A1 + nxt, &As[cur ^ 1][seg1 * 512]);
      gl_lds16(B0 + nxt, &Bs[cur ^ 1][seg0 * 512]);
      gl_lds16(B1 + nxt, &Bs[cur ^ 1][seg1 * 512]);
      asm volatile("s_waitcnt vmcnt(4)" ::: "memory");
    } else {
      asm volatile("s_waitcnt vmcnt(0)" ::: "memory");
    }
    __builtin_amdgcn_s_barrier();
    __builtin_amdgcn_sched_barrier(0);
    bf16x8 af[4], bfr[4];
#pragma unroll
    for (int i = 0; i < 4; ++i)
      af[i] = *reinterpret_cast<const bf16x8*>(&As[cur][aoff[i]]);
#pragma unroll
    for (int i = 0; i < 4; ++i)
      bfr[i] = *reinterpret_cast<const bf16x8*>(&Bs[cur][boff[i]]);
#pragma unroll
    for (int mi = 0; mi < 4; ++mi)
#pragma unroll
      for (int nj = 0; nj < 4; ++nj)
        acc[mi][nj] = __builtin_amdgcn_mfma_f32_16x16x32_bf16(
            af[mi], bfr[nj], acc[mi][nj], 0, 0, 0);
    __builtin_amdgcn_sched_barrier(0);
    __builtin_amdgcn_s_barrier();
    cur ^= 1;
  }

#pragma unroll
  for (int mi = 0; mi < 4; ++mi) {
#pragma unroll
    for (int nj = 0; nj < 4; ++nj) {
      int n = n0 + wc * 64 + nj * 16 + fr;
      if (n < Nreal) {
        if (PART) {
#pragma unroll
          for (int r = 0; r < 4; ++r) {
            int m = m0 + wr * 64 + mi * 16 + ks * 4 + r;
            Cb[(size_t)m * ldc + n] = f2bf(acc[mi][nj][r]);
          }
        } else if (QKV) {
          if (n < DMODEL) {
            float sc = (1.0f - 0.5f * (float)tmask[n]) * 0.125f;
#pragma unroll
            for (int r = 0; r < 4; ++r) {
              int m = m0 + wr * 64 + mi * 16 + ks * 4 + r;
              qb[(size_t)m * DMODEL + n] = f2bf(acc[mi][nj][r] * sc);
            }
          } else if (n < 2 * DMODEL) {
#pragma unroll
            for (int r = 0; r < 4; ++r) {
              int m = m0 + wr * 64 + mi * 16 + ks * 4 + r;
              kb[(size_t)m * DMODEL + (n - DMODEL)] = f2bf(acc[mi][nj][r]);
            }
          } else {
            int d = n - 2 * DMODEL;
            int key = (m0 & (SEQ - 1)) + wr * 64 + mi * 16 + ks * 4;
            size_t zr = (size_t)((m0 >> 10) * NHEAD + (d >> 6)) * 64 + (d & 63);
            ushort4 p4 = make_ushort4(
                f2bf(acc[mi][nj][0]), f2bf(acc[mi][nj][1]),
                f2bf(acc[mi][nj][2]), f2bf(acc[mi][nj][3]));
            *reinterpret_cast<ushort4*>(vt + zr * SEQ + key) = p4;
          }
        } else {
#pragma unroll
          for (int r = 0; r < 4; ++r) {
            int m = m0 + wr * 64 + mi * 16 + ks * 4 + r;
            float v = acc[mi][nj][r];
            if (BIAS) v += bias[n];
            if (GELU) v = 0.5f * v * (1.0f + erff(v * 0.70710678118f));
            if (RES) v += res[(size_t)m * ldc + n];
            if (OUTBF)
              Cb[(size_t)m * ldc + n] = f2bf(v);
            else
              Cf[(size_t)m * ldc + n] = v;
          }
        }
      }
    }
  }
}

// ---------------- LM head: 256x256, BK=64, 8-phase, coalesced epilogue ----
__global__ __launch_bounds__(512, 2) void gemm_lmhead(
    const ushort* __restrict__ A, const ushort* __restrict__ B,
    float* __restrict__ C) {
  __shared__ __align__(16) ushort SMEM[4 * 256 * 64];  // 128 KB
  const int K = DMODEL;      // 768
  const int NTILE = K / 64;  // 12
  const int ITERS = NTILE / 2;

  const int bid = blockIdx.x;
  const int chunk = gridDim.x >> 3;  // 197
  const int wgid = (bid & 7) * chunk + (bid >> 3);
  const int m0 = (wgid & 7) * 256;   // m fast -> B-panel reuse within XCD
  const int n0 = (wgid >> 3) * 256;

  const int tid = threadIdx.x;
  const int w = tid >> 6, l = tid & 63;
  const int wr = w >> 2, wc = w & 3;
  const int fr = l & 15, ks = l >> 4;

  const int strow = tid >> 3;                   // 0..63
  const int stk = ((tid & 7) ^ (strow & 7)) * 8;
  const int wseg = (w << 3) * 64;               // wave's 8-row LDS segment

  const int fsw0 = (ks ^ (fr & 7)) * 8;
  const int fsw1 = ((4 | ks) ^ (fr & 7)) * 8;
  const int arow = (wr * 128 + fr) * 64;  // + mi*16*64
  const int brow = (wc * 64 + fr) * 64;   // + nj*16*64

  bf16x8 Ar[4][2], Br[4][2];
  f32x4 acc[8][4] = {};

#define STA(d, kt, rb)                                            \
  gl_lds16(A + (size_t)(m0 + (rb) + strow) * K + (kt) * 64 + stk, \
           SMEM + (d) * 16384 + (rb) * 64 + wseg)
#define STB(d, kt, rb)                                            \
  gl_lds16(B + (size_t)(n0 + (rb) + strow) * K + (kt) * 64 + stk, \
           SMEM + 32768 + (d) * 16384 + (rb) * 64 + wseg)
#define RDA(d, mi, kst)                           \
  (*reinterpret_cast<const bf16x8*>(              \
      &SMEM[(d) * 16384 + arow + (mi) * 1024 + ((kst) ? fsw1 : fsw0)]))
#define RDB(d, nj, kst)                           \
  (*reinterpret_cast<const bf16x8*>(              \
      &SMEM[32768 + (d) * 16384 + brow + (nj) * 1024 + ((kst) ? fsw1 : fsw0)]))
#define MMAQ(mh, nh)                                                       \
  _Pragma("unroll") for (int kst = 0; kst < 2; ++kst)                      \
  _Pragma("unroll") for (int mi = 0; mi < 4; ++mi)                         \
  _Pragma("unroll") for (int nj = 0; nj < 2; ++nj)                         \
    acc[(mh)*4 + mi][(nh)*2 + nj] = __builtin_amdgcn_mfma_f32_16x16x32_bf16( \
        Ar[mi][kst], Br[(nh)*2 + nj][kst], acc[(mh)*4 + mi][(nh)*2 + nj],  \
        0, 0, 0)
#define BAR __builtin_amdgcn_s_barrier()
#define PRIO1 __builtin_amdgcn_s_setprio(1)
#define PRIO0 __builtin_amdgcn_s_setprio(0)

  STA(0, 0, 0); STA(0, 0, 64); STA(0, 0, 128); STA(0, 0, 192);
  STB(0, 0, 0); STB(0, 0, 64); STB(0, 0, 128); STB(0, 0, 192);
  STB(1, 1, 0); STB(1, 1, 64); STB(1, 1, 128); STB(1, 1, 192);
  asm volatile("s_waitcnt vmcnt(4)" ::: "memory");
  BAR;

  for (int it = 0; it < ITERS; ++it) {
    const int t1 = 2 * it + 1;
    const int tn = 2 * it + 2;
    const bool s0 = tn < NTILE, s1 = tn + 1 < NTILE;
#pragma unroll
    for (int mi = 0; mi < 4; ++mi) {
      Ar[mi][0] = RDA(0, mi, 0); Ar[mi][1] = RDA(0, mi, 1);
    }
#pragma unroll
    for (int nj = 0; nj < 2; ++nj) {
      Br[nj][0] = RDB(0, nj, 0); Br[nj][1] = RDB(0, nj, 1);
    }
    STA(1, t1, 0); STA(1, t1, 64);
    BAR; PRIO1; MMAQ(0, 0); PRIO0; BAR;
#pragma unroll
    for (int nj = 2; nj < 4; ++nj) {
      Br[nj][0] = RDB(0, nj, 0); Br[nj][1] = RDB(0, nj, 1);
    }
    STA(1, t1, 128); STA(1, t1, 192);
    BAR; PRIO1; MMAQ(0, 1); PRIO0; BAR;
#pragma unroll
    for (int mi = 0; mi < 4; ++mi) {
      Ar[mi][0] = RDA(0, mi + 4, 0); Ar[mi][1] = RDA(0, mi + 4, 1);
    }
    if (s0) { STB(0, tn, 0); STB(0, tn, 64); }
    BAR; PRIO1; MMAQ(1, 1); PRIO0; BAR;
    if (s0) { STB(0, tn, 128); STB(0, tn, 192); }
    BAR; PRIO1; MMAQ(1, 0); PRIO0;
    if (s0)
      asm volatile("s_waitcnt vmcnt(4)" ::: "memory");
    else
      asm volatile("s_waitcnt vmcnt(0)" ::: "memory");
    BAR;
#pragma unroll
    for (int mi = 0; mi < 4; ++mi) {
      Ar[mi][0] = RDA(1, mi, 0); Ar[mi][1] = RDA(1, mi, 1);
    }
#pragma unroll
    for (int nj = 0; nj < 2; ++nj) {
      Br[nj][0] = RDB(1, nj, 0); Br[nj][1] = RDB(1, nj, 1);
    }
    if (s0) { STA(0, tn, 0); STA(0, tn, 64); }
    BAR; PRIO1; MMAQ(0, 0); PRIO0; BAR;
#pragma unroll
    for (int nj = 2; nj < 4; ++nj) {
      Br[nj][0] = RDB(1, nj, 0); Br[nj][1] = RDB(1, nj, 1);
    }
    if (s0) { STA(0, tn, 128); STA(0, tn, 192); }
    BAR; PRIO1; MMAQ(0, 1); PRIO0; BAR;
#pragma unroll
    for (int mi = 0; mi < 4; ++mi) {
      Ar[mi][0] = RDA(1, mi + 4, 0); Ar[mi][1] = RDA(1, mi + 4, 1);
    }
    if (s1) { STB(1, tn + 1, 0); STB(1, tn + 1, 64); }
    BAR; PRIO1; MMAQ(1, 1); PRIO0; BAR;
    if (s1) { STB(1, tn + 1, 128); STB(1, tn + 1, 192); }
    BAR; PRIO1; MMAQ(1, 0); PRIO0;
    if (it + 1 < ITERS) {
      asm volatile("s_waitcnt vmcnt(4)" ::: "memory");
      BAR;
    }
  }

  // ---- coalesced epilogue: two 128-row halves through LDS ----
  float* eb = reinterpret_cast<float*>(SMEM);  // [128][256] fp32
#pragma unroll 1
  for (int p = 0; p < 2; ++p) {
    __syncthreads();
    if (wr == p) {
#pragma unroll
      for (int mi = 0; mi < 8; ++mi)
#pragma unroll
        for (int nj = 0; nj < 4; ++nj)
#pragma unroll
          for (int r = 0; r < 4; ++r)
            eb[(mi * 16 + ks * 4 + r) * 256 + wc * 64 + nj * 16 + fr] =
                acc[mi][nj][r];
    }
    __syncthreads();
    const size_t rowbase = (size_t)(m0 + p * 128) * VOCABSZ + n0;
#pragma unroll 8
    for (int c = 0; c < 64; ++c) {
      int lin = c * 512 + tid;
      int row = lin >> 8, col = lin & 255;
      if (n0 + col < VOCABSZ) {
        __builtin_nontemporal_store(
            eb[lin], C + rowbase + (size_t)row * VOCABSZ + col);
      }
    }
  }
#undef STA
#undef STB
#undef RDA
#undef RDB
#undef MMAQ
#undef BAR
#undef PRIO1
#undef PRIO0
}

// ---------------------------------------------------------------- launch
extern "C" void kernel_launch(void* const* d_in, const int* in_sizes, int n_in,
                              void* d_out, int out_size, void* d_ws,
                              size_t ws_size, hipStream_t stream) {
  const int* tokens = (const int*)d_in[0];
  const int* tmask = (const int*)d_in[1];
  const float* embed = (const float*)d_in[2];
  const float* pos = (const float*)d_in[3];
  const float* wq = (const float*)d_in[4];
  const float* wk = (const float*)d_in[5];
  const float* wv = (const float*)d_in[6];
  const float* wo = (const float*)d_in[7];
  const float* ln1g = (const float*)d_in[8];
  const float* ln1b = (const float*)d_in[9];
  const float* ln2g = (const float*)d_in[10];
  const float* ln2b = (const float*)d_in[11];
  const float* fw1 = (const float*)d_in[12];
  const float* fb1 = (const float*)d_in[13];
  const float* fw2 = (const float*)d_in[14];
  const float* fb2 = (const float*)d_in[15];
  const float* lnfg = (const float*)d_in[16];
  const float* lnfb = (const float*)d_in[17];

  char* wp = (char*)d_ws;
  auto alloc = [&](size_t bytes) {
    void* p = wp;
    wp += (bytes + 255) & ~(size_t)255;
    return p;
  };
  float* h = (float*)alloc((size_t)BT * DMODEL * 4);
  ushort* part = (ushort*)alloc((size_t)8 * BT * DMODEL * 2);
  ushort* qb = (ushort*)alloc((size_t)BT * DMODEL * 2);
  ushort* kb = (ushort*)alloc((size_t)BT * DMODEL * 2);
  ushort* vt = (ushort*)alloc((size_t)NBH * DHEAD * SEQ * 2);
  ushort* xn = (ushort*)alloc((size_t)BT * DMODEL * 2);
  ushort* ab = (ushort*)alloc((size_t)BT * DMODEL * 2);
  ushort* ffb = (ushort*)alloc((size_t)BT * DFFN * 2);
  ushort* wqkv_b = (ushort*)alloc((size_t)NLAYER * 3 * DMODEL * DMODEL * 2);
  ushort* wo_b = (ushort*)alloc((size_t)NLAYER * DMODEL * DMODEL * 2);
  ushort* fw1_b = (ushort*)alloc((size_t)NLAYER * DFFN * DMODEL * 2);
  ushort* fw2_b = (ushort*)alloc((size_t)NLAYER * DMODEL * DFFN * 2);
  ushort* emb_b = (ushort*)alloc((size_t)VPAD * DMODEL * 2);

  const int per4 = DMODEL * DMODEL / 4;
  const int nff4 = NLAYER * DFFN * DMODEL / 4;
  conv_qkv3_kernel<<<(3 * NLAYER * per4 + 255) / 256, 256, 0, stream>>>(
      wq, wk, wv, wqkv_b);
  conv3_kernel<<<(NLAYER * per4 + 2 * nff4 + 255) / 256, 256, 0, stream>>>(
      wo, wo_b, fw1, fw1_b, fw2, fw2_b);
  conv_embed_kernel<<<(VPAD * DMODEL / 4 + 255) / 256, 256, 0, stream>>>(
      embed, emb_b);

  const dim3 gqkv(3 * DMODEL / 128, BT / 128);
  const dim3 gff(DFFN / 128, BT / 128);
  const dim3 gwo(DMODEL / 128, BT / 128, 4);   // wo split-K x4 (6 steps/blk)
  const dim3 gff2(DMODEL / 128, BT / 128, 8);  // ff2 split-K x8 (12 steps/blk)

  for (int i = 0; i < NLAYER; ++i) {
    if (i == 0)
      ln_kernel<0, false, true><<<BT, 256, 0, stream>>>(
          h, nullptr, nullptr, tokens, embed, pos, ln1g, ln1b, xn);
    else
      ln_kernel<8, true, false><<<BT, 256, 0, stream>>>(
          h, part, fb2 + (i - 1) * DMODEL, nullptr, nullptr, nullptr,
          ln1g + i * DMODEL, ln1b + i * DMODEL, xn);

    gemm_bf16_nt<true, false, false, false, false, false, false>
        <<<gqkv, 256, 0, stream>>>(
            xn, wqkv_b + (size_t)i * 3 * DMODEL * DMODEL, nullptr,
            tmask + i * DMODEL, nullptr, nullptr, nullptr, 0, qb, kb, vt, BT,
            DMODEL, 3 * DMODEL, DMODEL);

    fattn_kernel<<<NBH * (SEQ / 64), 256, 0, stream>>>(qb, kb, vt, ab);

    gemm_bf16_nt<false, false, false, false, false, false, true>
        <<<gwo, 256, 0, stream>>>(
            ab, wo_b + (size_t)i * DMODEL * DMODEL, nullptr, nullptr, nullptr,
            nullptr, part, DMODEL, nullptr, nullptr, nullptr, BT, DMODEL,
            DMODEL, DMODEL / 4);

    ln_kernel<4, false, false><<<BT, 256, 0, stream>>>(
        h, part, nullptr, nullptr, nullptr, nullptr, ln2g + i * DMODEL,
        ln2b + i * DMODEL, xn);

    gemm_bf16_nt<false, true, true, false, true, false, false>
        <<<gff, 256, 0, stream>>>(
            xn, fw1_b + (size_t)i * DFFN * DMODEL, fb1 + i * DFFN, nullptr,
            nullptr, nullptr, ffb, DFFN, nullptr, nullptr, nullptr, BT, DMODEL,
            DFFN, DMODEL);

    gemm_bf16_nt<false, false, false, false, false, false, true>
        <<<gff2, 256, 0, stream>>>(
            ffb, fw2_b + (size_t)i * DMODEL * DFFN, nullptr, nullptr, nullptr,
            nullptr, part, DMODEL, nullptr, nullptr, nullptr, BT, DFFN, DMODEL,
            DFFN / 8);
  }

  ln_kernel<8, true, false><<<BT, 256, 0, stream>>>(
      h, part, fb2 + (NLAYER - 1) * DMODEL, nullptr, nullptr, nullptr, lnfg,
      lnfb, xn);

  gemm_lmhead<<<8 * (VPAD / 256), 512, 0, stream>>>(xn, emb_b, (float*)d_out);
}

// Round 16
// 837.640 us; speedup vs baseline: 1.0685x; 1.0024x over previous
//
#include <hip/hip_runtime.h>
#include <math.h>

#define VOCABSZ 50257
#define VPAD 50432
#define DMODEL 768
#define NHEAD 12
#define NLAYER 4
#define SEQ 1024
#define BATCH 2
#define DHEAD 64
#define DFFN 3072
#define BT (BATCH * SEQ)
#define NBH (BATCH * NHEAD)

typedef __attribute__((ext_vector_type(8))) short bf16x8;
typedef __attribute__((ext_vector_type(4))) float f32x4;

__device__ __forceinline__ ushort f2bf(float f) {
  uint u = __builtin_bit_cast(uint, f);
  u = (u + 0x7fffu + ((u >> 16) & 1u)) >> 16;
  return (ushort)u;
}

__device__ __forceinline__ float bf2f(ushort u) {
  uint x = ((uint)u) << 16;
  return __builtin_bit_cast(float, x);
}

__device__ __forceinline__ void gl_lds16(const ushort* g, ushort* l) {
  __builtin_amdgcn_global_load_lds(
      (const __attribute__((address_space(1))) void*)g,
      (__attribute__((address_space(3))) void*)l, 16, 0, 0);
}

// ------------------------------------------------------------- conversions
__global__ __launch_bounds__(256) void conv_qkv3_kernel(
    const float* __restrict__ wq, const float* __restrict__ wk,
    const float* __restrict__ wv, ushort* __restrict__ dst) {
  const int per4 = DMODEL * DMODEL / 4;
  const int total = NLAYER * per4;
  int i = blockIdx.x * 256 + threadIdx.x;
  if (i >= 3 * total) return;
  int which = i / total;
  int rem = i - which * total;
  const float* src = (which == 0) ? wq : (which == 1) ? wk : wv;
  int layer = rem / per4, r2 = rem % per4;
  float4 v = reinterpret_cast<const float4*>(src)[rem];
  reinterpret_cast<ushort4*>(dst)[(size_t)layer * (3 * per4) + which * per4 +
                                  r2] =
      make_ushort4(f2bf(v.x), f2bf(v.y), f2bf(v.z), f2bf(v.w));
}

__global__ __launch_bounds__(256) void conv3_kernel(
    const float* __restrict__ wo, ushort* __restrict__ wo_b,
    const float* __restrict__ fw1, ushort* __restrict__ fw1_b,
    const float* __restrict__ fw2, ushort* __restrict__ fw2_b) {
  const int n1 = NLAYER * DMODEL * DMODEL / 4;
  const int nf = NLAYER * DFFN * DMODEL / 4;
  int i = blockIdx.x * 256 + threadIdx.x;
  const float* src;
  ushort* dst;
  int idx;
  if (i < n1) {
    src = wo; dst = wo_b; idx = i;
  } else if (i < n1 + nf) {
    src = fw1; dst = fw1_b; idx = i - n1;
  } else if (i < n1 + 2 * nf) {
    src = fw2; dst = fw2_b; idx = i - n1 - nf;
  } else {
    return;
  }
  float4 v = reinterpret_cast<const float4*>(src)[idx];
  reinterpret_cast<ushort4*>(dst)[idx] =
      make_ushort4(f2bf(v.x), f2bf(v.y), f2bf(v.z), f2bf(v.w));
}

__global__ __launch_bounds__(256) void conv_embed_kernel(
    const float* __restrict__ emb, ushort* __restrict__ dst) {
  int i = blockIdx.x * 256 + threadIdx.x;
  if (i >= VPAD * DMODEL / 4) return;
  int row = (i * 4) / DMODEL;
  ushort4 o = make_ushort4(0, 0, 0, 0);
  if (row < VOCABSZ) {
    float4 v = reinterpret_cast<const float4*>(emb)[i];
    o = make_ushort4(f2bf(v.x), f2bf(v.y), f2bf(v.z), f2bf(v.w));
  }
  reinterpret_cast<ushort4*>(dst)[i] = o;
}

// --------------- layernorm (+ fused split-K reduce / embedding, bf16 parts)
template <int KS, bool RBIAS, bool EMB>
__global__ __launch_bounds__(256) void ln_kernel(
    float* __restrict__ h, const ushort* __restrict__ part,
    const float* __restrict__ rb, const int* __restrict__ tok,
    const float* __restrict__ emb, const float* __restrict__ pos,
    const float* __restrict__ g, const float* __restrict__ bta,
    ushort* __restrict__ o) {
  __shared__ float red[8];
  int row = blockIdx.x;
  int tid = threadIdx.x;
  float* xr = h + (size_t)row * DMODEL;
  const float* er = nullptr;
  const float* pr = nullptr;
  if (EMB) {
    er = emb + (size_t)tok[row] * DMODEL;
    pr = pos + (size_t)(row & (SEQ - 1)) * DMODEL;
  }
  float v[3];
  float s = 0.f, sq = 0.f;
#pragma unroll
  for (int j = 0; j < 3; ++j) {
    int c = tid + j * 256;
    float a;
    if (EMB) {
      a = er[c] + pr[c];
      xr[c] = a;
    } else {
      a = xr[c];
      if (RBIAS) a += rb[c];
      if (KS > 0) {
#pragma unroll
        for (int z = 0; z < KS; ++z)
          a += bf2f(part[(size_t)z * BT * DMODEL + (size_t)row * DMODEL + c]);
        xr[c] = a;
      }
    }
    v[j] = a;
    s += a;
    sq += a * a;
  }
#pragma unroll
  for (int off = 1; off < 64; off <<= 1) {
    s += __shfl_xor(s, off);
    sq += __shfl_xor(sq, off);
  }
  int wid = tid >> 6;
  if ((tid & 63) == 0) { red[wid * 2] = s; red[wid * 2 + 1] = sq; }
  __syncthreads();
  float S = red[0] + red[2] + red[4] + red[6];
  float SQ = red[1] + red[3] + red[5] + red[7];
  float mu = S * (1.0f / DMODEL);
  float var = SQ * (1.0f / DMODEL) - mu * mu;
  float r = rsqrtf(var + 1e-5f);
  ushort* orow = o + (size_t)row * DMODEL;
#pragma unroll
  for (int j = 0; j < 3; ++j) {
    int c = tid + j * 256;
    orow[c] = f2bf((v[j] - mu) * r * g[c] + bta[c]);
  }
}

// ------------- flash attention, K-range split x2 + unnormalized partials ---
// grid 768 = 8 XCD x 96 (3 z x 16 qblocks x 2 splits per XCD chunk).
__global__ __launch_bounds__(256) void fattn_kernel(
    const ushort* __restrict__ q, const ushort* __restrict__ k,
    const ushort* __restrict__ vt, float* __restrict__ Opart,
    float* __restrict__ ml) {
  __shared__ __align__(16) ushort Ks[2][64 * 64];
  __shared__ __align__(16) ushort Vs[2][64 * 64];
  __shared__ __align__(16) ushort Ps[4][16][80];
  const int bid = blockIdx.x;
  const int wgid = (bid & 7) * 96 + (bid >> 3);
  const int z = wgid / 32;
  const int rem = wgid % 32;
  const int qb_ = rem >> 1, s = rem & 1;
  const int b = z / NHEAD, hh = z % NHEAD;
  const int q0 = (15 - qb_) * 64;  // long blocks first within chunk
  const int tcnt = (q0 >> 6) + 1;
  const int half0 = (tcnt + 1) >> 1;
  const int tbeg = s ? half0 : 0;
  const int tend = s ? tcnt : half0;
  const int tid = threadIdx.x, w = tid >> 6, l = tid & 63;
  const int fr = l & 15, ks = l >> 4;
  const int qrow = q0 + w * 16 + fr;
  const size_t ri = (size_t)z * SEQ + qrow;
  const size_t R = (size_t)NBH * SEQ;
  const size_t off = (s ? R : 0) + ri;

  if (tbeg >= tend) {  // empty split (tcnt==1, s==1)
    f32x4 zero = {};
#pragma unroll
    for (int db = 0; db < 4; ++db)
      *reinterpret_cast<f32x4*>(Opart + off * 64 + db * 16 + ks * 4) = zero;
    if (ks == 0) { ml[off * 2] = -1e30f; ml[off * 2 + 1] = 0.f; }
    return;
  }

  const ushort* qp = q + (size_t)(b * SEQ + qrow) * DMODEL + hh * DHEAD;
  const bf16x8 qf0 = *reinterpret_cast<const bf16x8*>(qp + ks * 8);
  const bf16x8 qf1 = *reinterpret_cast<const bf16x8*>(qp + 32 + ks * 8);

  const int srow = w * 16 + (l >> 3);
  const int g0 = ((l & 7) ^ (srow & 7)) * 8;

  auto stage = [&](int k0, int d) {
#pragma unroll
    for (int c = 0; c < 2; ++c) {
      int r = srow + c * 8;
      gl_lds16(k + (size_t)(b * SEQ + k0 + r) * DMODEL + hh * DHEAD + g0,
               &Ks[d][(w * 16 + c * 8) * 64]);
      gl_lds16(vt + (size_t)(z * 64 + r) * SEQ + k0 + g0,
               &Vs[d][(w * 16 + c * 8) * 64]);
    }
  };

  f32x4 acc_o[4] = {};
  float mrun = -1e30f, lrun = 0.f;

  stage(tbeg * 64, 0);
  for (int t = tbeg; t < tend; ++t) {
    const int cur = (t - tbeg) & 1;
    if (t + 1 < tend) {
      stage((t + 1) * 64, cur ^ 1);
      asm volatile("s_waitcnt vmcnt(4)" ::: "memory");
    } else {
      asm volatile("s_waitcnt vmcnt(0)" ::: "memory");
    }
    __builtin_amdgcn_s_barrier();
    __builtin_amdgcn_sched_barrier(0);
    f32x4 acc_s[4] = {};
#pragma unroll
    for (int kstep = 0; kstep < 2; ++kstep) {
      const bf16x8 qf = kstep ? qf1 : qf0;
#pragma unroll
      for (int kb = 0; kb < 4; ++kb) {
        int ra = kb * 16 + fr;
        bf16x8 af = *reinterpret_cast<const bf16x8*>(
            &Ks[cur][ra * 64 + (((kstep * 4 + ks) ^ (ra & 7)) * 8)]);
        acc_s[kb] =
            __builtin_amdgcn_mfma_f32_16x16x32_bf16(af, qf, acc_s[kb], 0, 0, 0);
      }
    }
    const bool diag = (t == tcnt - 1);
    float pm = -1e30f;
    float sv[4][4];
#pragma unroll
    for (int kb = 0; kb < 4; ++kb)
#pragma unroll
      for (int r = 0; r < 4; ++r) {
        float sc = acc_s[kb][r];
        if (diag && (t * 64 + kb * 16 + ks * 4 + r > qrow)) sc = -1e30f;
        sv[kb][r] = sc;
        pm = fmaxf(pm, sc);
      }
    pm = fmaxf(pm, __shfl_xor(pm, 16));
    pm = fmaxf(pm, __shfl_xor(pm, 32));
    if (!__all(pm - mrun <= 8.0f)) {
      float mnew = fmaxf(mrun, pm);
      float scale = __expf(mrun - mnew);
      lrun *= scale;
#pragma unroll
      for (int db = 0; db < 4; ++db) acc_o[db] *= scale;
      mrun = mnew;
    }
    float psum = 0.f;
#pragma unroll
    for (int kb = 0; kb < 4; ++kb) {
      float p0 = __expf(sv[kb][0] - mrun);
      float p1 = __expf(sv[kb][1] - mrun);
      float p2 = __expf(sv[kb][2] - mrun);
      float p3 = __expf(sv[kb][3] - mrun);
      psum += (p0 + p1) + (p2 + p3);
      *reinterpret_cast<ushort4*>(&Ps[w][fr][kb * 16 + ks * 4]) =
          make_ushort4(f2bf(p0), f2bf(p1), f2bf(p2), f2bf(p3));
    }
    psum += __shfl_xor(psum, 16);
    psum += __shfl_xor(psum, 32);
    lrun += psum;
#pragma unroll
    for (int kstep = 0; kstep < 2; ++kstep) {
      bf16x8 pf =
          *reinterpret_cast<const bf16x8*>(&Ps[w][fr][kstep * 32 + ks * 8]);
#pragma unroll
      for (int db = 0; db < 4; ++db) {
        int rd = db * 16 + fr;
        bf16x8 vf = *reinterpret_cast<const bf16x8*>(
            &Vs[cur][rd * 64 + (((kstep * 4 + ks) ^ (rd & 7)) * 8)]);
        acc_o[db] =
            __builtin_amdgcn_mfma_f32_16x16x32_bf16(vf, pf, acc_o[db], 0, 0, 0);
      }
    }
    __builtin_amdgcn_sched_barrier(0);
    __builtin_amdgcn_s_barrier();
  }
#pragma unroll
  for (int db = 0; db < 4; ++db)
    *reinterpret_cast<f32x4*>(Opart + off * 64 + db * 16 + ks * 4) = acc_o[db];
  if (ks == 0) { ml[off * 2] = mrun; ml[off * 2 + 1] = lrun; }
}

// ---------------- merge the two K-range splits (exact flash merge) --------
__global__ __launch_bounds__(256) void fmerge_kernel(
    const float* __restrict__ Opart, const float* __restrict__ ml,
    ushort* __restrict__ o) {
  int ri = blockIdx.x * 4 + (threadIdx.x >> 6);
  int d = threadIdx.x & 63;
  int z = ri >> 10, qrow = ri & (SEQ - 1);
  int b = z / NHEAD, hh = z % NHEAD;
  const size_t R = (size_t)NBH * SEQ;
  float m0 = ml[(size_t)ri * 2], l0 = ml[(size_t)ri * 2 + 1];
  float m1 = ml[(R + ri) * 2], l1 = ml[(R + ri) * 2 + 1];
  float M = fmaxf(m0, m1);
  float e0 = __expf(m0 - M), e1 = __expf(m1 - M);
  float L = l0 * e0 + l1 * e1;
  float v0 = Opart[(size_t)ri * 64 + d];
  float v1 = Opart[(R + ri) * 64 + d];
  float v = (v0 * e0 + v1 * e1) / L;
  o[(size_t)(b * SEQ + qrow) * DMODEL + hh * DHEAD + d] = f2bf(v);
}

// ------------------------------------------------------- bf16 MFMA NT GEMM
template <bool QKV, bool BIAS, bool GELU, bool RES, bool OUTBF, bool SWZ,
          bool PART>
__global__ __launch_bounds__(256) void gemm_bf16_nt(
    const ushort* __restrict__ A, const ushort* __restrict__ B,
    const float* __restrict__ bias, const int* __restrict__ tmask,
    const float* __restrict__ res, float* __restrict__ Cf,
    ushort* __restrict__ Cb, int ldc, ushort* __restrict__ qb,
    ushort* __restrict__ kb, ushort* __restrict__ vt, int M, int K, int Nreal,
    int kchunk) {
  __shared__ __align__(16) ushort As[2][128 * 32];
  __shared__ __align__(16) ushort Bs[2][128 * 32];
  int bnx, bmy;
  if (SWZ) {
    int bid = blockIdx.x;
    int chunk = gridDim.x >> 3;
    int wgid = (bid & 7) * chunk + (bid >> 3);
    int mb = M >> 7;
    bmy = wgid % mb;
    bnx = wgid / mb;
  } else {
    bnx = blockIdx.x;
    bmy = blockIdx.y;
  }
  const int m0 = bmy * 128, n0 = bnx * 128;
  const int kbeg = PART ? blockIdx.z * kchunk : 0;
  const int kend = PART ? kbeg + kchunk : K;
  if (PART) Cb += (size_t)blockIdx.z * M * ldc;
  const int tid = threadIdx.x;
  const int w = tid >> 6, l = tid & 63;
  const int wr = w >> 1, wc = w & 1;
  const int fr = l & 15, ks = l >> 4;

  const int seg0 = w * 2, seg1 = w * 2 + 1;
  const int srow0 = seg0 * 16 + (l >> 2);
  const int srow1 = seg1 * 16 + (l >> 2);
  const int koff0 = (((l & 3) ^ ((srow0 >> 1) & 3))) * 8;
  const int koff1 = (((l & 3) ^ ((srow1 >> 1) & 3))) * 8;
  const ushort* A0 = A + (size_t)(m0 + srow0) * K + koff0;
  const ushort* A1 = A + (size_t)(m0 + srow1) * K + koff1;
  const ushort* B0 = B + (size_t)(n0 + srow0) * K + koff0;
  const ushort* B1 = B + (size_t)(n0 + srow1) * K + koff1;

  int aoff[4], boff[4];
#pragma unroll
  for (int i = 0; i < 4; ++i) {
    int ra = wr * 64 + i * 16 + fr;
    aoff[i] = ra * 32 + ((ks ^ ((ra >> 1) & 3)) * 8);
    int rb = wc * 64 + i * 16 + fr;
    boff[i] = rb * 32 + ((ks ^ ((rb >> 1) & 3)) * 8);
  }

  gl_lds16(A0 + kbeg, &As[0][seg0 * 512]);
  gl_lds16(A1 + kbeg, &As[0][seg1 * 512]);
  gl_lds16(B0 + kbeg, &Bs[0][seg0 * 512]);
  gl_lds16(B1 + kbeg, &Bs[0][seg1 * 512]);

  f32x4 acc[4][4] = {};
  int cur = 0;
  for (int k0 = kbeg; k0 < kend; k0 += 32) {
    const int nxt = k0 + 32;
    if (nxt < kend) {
      gl_lds16(A0 + nxt, &As[cur ^ 1][seg0 * 512]);
      gl_lds16(A1 + nxt, &As[cur ^ 1][seg1 * 512]);
      gl_lds16(B0 + nxt, &Bs[cur ^ 1][seg0 * 512]);
      gl_lds16(B1 + nxt, &Bs[cur ^ 1][seg1 * 512]);
      asm volatile("s_waitcnt vmcnt(4)" ::: "memory");
    } else {
      asm volatile("s_waitcnt vmcnt(0)" ::: "memory");
    }
    __builtin_amdgcn_s_barrier();
    __builtin_amdgcn_sched_barrier(0);
    bf16x8 af[4], bfr[4];
#pragma unroll
    for (int i = 0; i < 4; ++i)
      af[i] = *reinterpret_cast<const bf16x8*>(&As[cur][aoff[i]]);
#pragma unroll
    for (int i = 0; i < 4; ++i)
      bfr[i] = *reinterpret_cast<const bf16x8*>(&Bs[cur][boff[i]]);
#pragma unroll
    for (int mi = 0; mi < 4; ++mi)
#pragma unroll
      for (int nj = 0; nj < 4; ++nj)
        acc[mi][nj] = __builtin_amdgcn_mfma_f32_16x16x32_bf16(
            af[mi], bfr[nj], acc[mi][nj], 0, 0, 0);
    __builtin_amdgcn_sched_barrier(0);
    __builtin_amdgcn_s_barrier();
    cur ^= 1;
  }

#pragma unroll
  for (int mi = 0; mi < 4; ++mi) {
#pragma unroll
    for (int nj = 0; nj < 4; ++nj) {
      int n = n0 + wc * 64 + nj * 16 + fr;
      if (n < Nreal) {
        if (PART) {
#pragma unroll
          for (int r = 0; r < 4; ++r) {
            int m = m0 + wr * 64 + mi * 16 + ks * 4 + r;
            Cb[(size_t)m * ldc + n] = f2bf(acc[mi][nj][r]);
          }
        } else if (QKV) {
          if (n < DMODEL) {
            float sc = (1.0f - 0.5f * (float)tmask[n]) * 0.125f;
#pragma unroll
            for (int r = 0; r < 4; ++r) {
              int m = m0 + wr * 64 + mi * 16 + ks * 4 + r;
              qb[(size_t)m * DMODEL + n] = f2bf(acc[mi][nj][r] * sc);
            }
          } else if (n < 2 * DMODEL) {
#pragma unroll
            for (int r = 0; r < 4; ++r) {
              int m = m0 + wr * 64 + mi * 16 + ks * 4 + r;
              kb[(size_t)m * DMODEL + (n - DMODEL)] = f2bf(acc[mi][nj][r]);
            }
          } else {
            int d = n - 2 * DMODEL;
            int key = (m0 & (SEQ - 1)) + wr * 64 + mi * 16 + ks * 4;
            size_t zr = (size_t)((m0 >> 10) * NHEAD + (d >> 6)) * 64 + (d & 63);
            ushort4 p4 = make_ushort4(
                f2bf(acc[mi][nj][0]), f2bf(acc[mi][nj][1]),
                f2bf(acc[mi][nj][2]), f2bf(acc[mi][nj][3]));
            *reinterpret_cast<ushort4*>(vt + zr * SEQ + key) = p4;
          }
        } else {
#pragma unroll
          for (int r = 0; r < 4; ++r) {
            int m = m0 + wr * 64 + mi * 16 + ks * 4 + r;
            float v = acc[mi][nj][r];
            if (BIAS) v += bias[n];
            if (GELU) v = 0.5f * v * (1.0f + erff(v * 0.70710678118f));
            if (RES) v += res[(size_t)m * ldc + n];
            if (OUTBF)
              Cb[(size_t)m * ldc + n] = f2bf(v);
            else
              Cf[(size_t)m * ldc + n] = v;
          }
        }
      }
    }
  }
}

// ---------------- LM head: 256x256, BK=64, 8-phase, coalesced epilogue ----
__global__ __launch_bounds__(512, 2) void gemm_lmhead(
    const ushort* __restrict__ A, const ushort* __restrict__ B,
    float* __restrict__ C) {
  __shared__ __align__(16) ushort SMEM[4 * 256 * 64];  // 128 KB
  const int K = DMODEL;      // 768
  const int NTILE = K / 64;  // 12
  const int ITERS = NTILE / 2;

  const int bid = blockIdx.x;
  const int chunk = gridDim.x >> 3;  // 197
  const int wgid = (bid & 7) * chunk + (bid >> 3);
  const int m0 = (wgid & 7) * 256;   // m fast -> B-panel reuse within XCD
  const int n0 = (wgid >> 3) * 256;

  const int tid = threadIdx.x;
  const int w = tid >> 6, l = tid & 63;
  const int wr = w >> 2, wc = w & 3;
  const int fr = l & 15, ks = l >> 4;

  const int strow = tid >> 3;                   // 0..63
  const int stk = ((tid & 7) ^ (strow & 7)) * 8;
  const int wseg = (w << 3) * 64;               // wave's 8-row LDS segment

  const int fsw0 = (ks ^ (fr & 7)) * 8;
  const int fsw1 = ((4 | ks) ^ (fr & 7)) * 8;
  const int arow = (wr * 128 + fr) * 64;  // + mi*16*64
  const int brow = (wc * 64 + fr) * 64;   // + nj*16*64

  bf16x8 Ar[4][2], Br[4][2];
  f32x4 acc[8][4] = {};

#define STA(d, kt, rb)                                            \
  gl_lds16(A + (size_t)(m0 + (rb) + strow) * K + (kt) * 64 + stk, \
           SMEM + (d) * 16384 + (rb) * 64 + wseg)
#define STB(d, kt, rb)                                            \
  gl_lds16(B + (size_t)(n0 + (rb) + strow) * K + (kt) * 64 + stk, \
           SMEM + 32768 + (d) * 16384 + (rb) * 64 + wseg)
#define RDA(d, mi, kst)                           \
  (*reinterpret_cast<const bf16x8*>(              \
      &SMEM[(d) * 16384 + arow + (mi) * 1024 + ((kst) ? fsw1 : fsw0)]))
#define RDB(d, nj, kst)                           \
  (*reinterpret_cast<const bf16x8*>(              \
      &SMEM[32768 + (d) * 16384 + brow + (nj) * 1024 + ((kst) ? fsw1 : fsw0)]))
#define MMAQ(mh, nh)                                                       \
  _Pragma("unroll") for (int kst = 0; kst < 2; ++kst)                      \
  _Pragma("unroll") for (int mi = 0; mi < 4; ++mi)                         \
  _Pragma("unroll") for (int nj = 0; nj < 2; ++nj)                         \
    acc[(mh)*4 + mi][(nh)*2 + nj] = __builtin_amdgcn_mfma_f32_16x16x32_bf16( \
        Ar[mi][kst], Br[(nh)*2 + nj][kst], acc[(mh)*4 + mi][(nh)*2 + nj],  \
        0, 0, 0)
#define BAR __builtin_amdgcn_s_barrier()
#define PRIO1 __builtin_amdgcn_s_setprio(1)
#define PRIO0 __builtin_amdgcn_s_setprio(0)

  STA(0, 0, 0); STA(0, 0, 64); STA(0, 0, 128); STA(0, 0, 192);
  STB(0, 0, 0); STB(0, 0, 64); STB(0, 0, 128); STB(0, 0, 192);
  STB(1, 1, 0); STB(1, 1, 64); STB(1, 1, 128); STB(1, 1, 192);
  asm volatile("s_waitcnt vmcnt(4)" ::: "memory");
  BAR;

  for (int it = 0; it < ITERS; ++it) {
    const int t1 = 2 * it + 1;
    const int tn = 2 * it + 2;
    const bool s0 = tn < NTILE, s1 = tn + 1 < NTILE;
#pragma unroll
    for (int mi = 0; mi < 4; ++mi) {
      Ar[mi][0] = RDA(0, mi, 0); Ar[mi][1] = RDA(0, mi, 1);
    }
#pragma unroll
    for (int nj = 0; nj < 2; ++nj) {
      Br[nj][0] = RDB(0, nj, 0); Br[nj][1] = RDB(0, nj, 1);
    }
    STA(1, t1, 0); STA(1, t1, 64);
    BAR; PRIO1; MMAQ(0, 0); PRIO0; BAR;
#pragma unroll
    for (int nj = 2; nj < 4; ++nj) {
      Br[nj][0] = RDB(0, nj, 0); Br[nj][1] = RDB(0, nj, 1);
    }
    STA(1, t1, 128); STA(1, t1, 192);
    BAR; PRIO1; MMAQ(0, 1); PRIO0; BAR;
#pragma unroll
    for (int mi = 0; mi < 4; ++mi) {
      Ar[mi][0] = RDA(0, mi + 4, 0); Ar[mi][1] = RDA(0, mi + 4, 1);
    }
    if (s0) { STB(0, tn, 0); STB(0, tn, 64); }
    BAR; PRIO1; MMAQ(1, 1); PRIO0; BAR;
    if (s0) { STB(0, tn, 128); STB(0, tn, 192); }
    BAR; PRIO1; MMAQ(1, 0); PRIO0;
    if (s0)
      asm volatile("s_waitcnt vmcnt(4)" ::: "memory");
    else
      asm volatile("s_waitcnt vmcnt(0)" ::: "memory");
    BAR;
#pragma unroll
    for (int mi = 0; mi < 4; ++mi) {
      Ar[mi][0] = RDA(1, mi, 0); Ar[mi][1] = RDA(1, mi, 1);
    }
#pragma unroll
    for (int nj = 0; nj < 2; ++nj) {
      Br[nj][0] = RDB(1, nj, 0); Br[nj][1] = RDB(1, nj, 1);
    }
    if (s0) { STA(0, tn, 0); STA(0, tn, 64); }
    BAR; PRIO1; MMAQ(0, 0); PRIO0; BAR;
#pragma unroll
    for (int nj = 2; nj < 4; ++nj) {
      Br[nj][0] = RDB(1, nj, 0); Br[nj][1] = RDB(1, nj, 1);
    }
    if (s0) { STA(0, tn, 128); STA(0, tn, 192); }
    BAR; PRIO1; MMAQ(0, 1); PRIO0; BAR;
#pragma unroll
    for (int mi = 0; mi < 4; ++mi) {
      Ar[mi][0] = RDA(1, mi + 4, 0); Ar[mi][1] = RDA(1, mi + 4, 1);
    }
    if (s1) { STB(1, tn + 1, 0); STB(1, tn + 1, 64); }
    BAR; PRIO1; MMAQ(1, 1); PRIO0; BAR;
    if (s1) { STB(1, tn + 1, 128); STB(1, tn + 1, 192); }
    BAR; PRIO1; MMAQ(1, 0); PRIO0;
    if (it + 1 < ITERS) {
      asm volatile("s_waitcnt vmcnt(4)" ::: "memory");
      BAR;
    }
  }

  // ---- coalesced epilogue: two 128-row halves through LDS ----
  float* eb = reinterpret_cast<float*>(SMEM);  // [128][256] fp32
#pragma unroll 1
  for (int p = 0; p < 2; ++p) {
    __syncthreads();
    if (wr == p) {
#pragma unroll
      for (int mi = 0; mi < 8; ++mi)
#pragma unroll
        for (int nj = 0; nj < 4; ++nj)
#pragma unroll
          for (int r = 0; r < 4; ++r)
            eb[(mi * 16 + ks * 4 + r) * 256 + wc * 64 + nj * 16 + fr] =
                acc[mi][nj][r];
    }
    __syncthreads();
    const size_t rowbase = (size_t)(m0 + p * 128) * VOCABSZ + n0;
#pragma unroll 8
    for (int c = 0; c < 64; ++c) {
      int lin = c * 512 + tid;
      int row = lin >> 8, col = lin & 255;
      if (n0 + col < VOCABSZ) {
        __builtin_nontemporal_store(
            eb[lin], C + rowbase + (size_t)row * VOCABSZ + col);
      }
    }
  }
#undef STA
#undef STB
#undef RDA
#undef RDB
#undef MMAQ
#undef BAR
#undef PRIO1
#undef PRIO0
}

// ---------------------------------------------------------------- launch
extern "C" void kernel_launch(void* const* d_in, const int* in_sizes, int n_in,
                              void* d_out, int out_size, void* d_ws,
                              size_t ws_size, hipStream_t stream) {
  const int* tokens = (const int*)d_in[0];
  const int* tmask = (const int*)d_in[1];
  const float* embed = (const float*)d_in[2];
  const float* pos = (const float*)d_in[3];
  const float* wq = (const float*)d_in[4];
  const float* wk = (const float*)d_in[5];
  const float* wv = (const float*)d_in[6];
  const float* wo = (const float*)d_in[7];
  const float* ln1g = (const float*)d_in[8];
  const float* ln1b = (const float*)d_in[9];
  const float* ln2g = (const float*)d_in[10];
  const float* ln2b = (const float*)d_in[11];
  const float* fw1 = (const float*)d_in[12];
  const float* fb1 = (const float*)d_in[13];
  const float* fw2 = (const float*)d_in[14];
  const float* fb2 = (const float*)d_in[15];
  const float* lnfg = (const float*)d_in[16];
  const float* lnfb = (const float*)d_in[17];

  char* wp = (char*)d_ws;
  auto alloc = [&](size_t bytes) {
    void* p = wp;
    wp += (bytes + 255) & ~(size_t)255;
    return p;
  };
  float* h = (float*)alloc((size_t)BT * DMODEL * 4);
  ushort* part = (ushort*)alloc((size_t)8 * BT * DMODEL * 2);
  float* opart = (float*)alloc((size_t)2 * NBH * SEQ * DHEAD * 4);
  float* mlb = (float*)alloc((size_t)2 * NBH * SEQ * 2 * 4);
  ushort* qb = (ushort*)alloc((size_t)BT * DMODEL * 2);
  ushort* kb = (ushort*)alloc((size_t)BT * DMODEL * 2);
  ushort* vt = (ushort*)alloc((size_t)NBH * DHEAD * SEQ * 2);
  ushort* xn = (ushort*)alloc((size_t)BT * DMODEL * 2);
  ushort* ab = (ushort*)alloc((size_t)BT * DMODEL * 2);
  ushort* ffb = (ushort*)alloc((size_t)BT * DFFN * 2);
  ushort* wqkv_b = (ushort*)alloc((size_t)NLAYER * 3 * DMODEL * DMODEL * 2);
  ushort* wo_b = (ushort*)alloc((size_t)NLAYER * DMODEL * DMODEL * 2);
  ushort* fw1_b = (ushort*)alloc((size_t)NLAYER * DFFN * DMODEL * 2);
  ushort* fw2_b = (ushort*)alloc((size_t)NLAYER * DMODEL * DFFN * 2);
  ushort* emb_b = (ushort*)alloc((size_t)VPAD * DMODEL * 2);

  const int per4 = DMODEL * DMODEL / 4;
  const int nff4 = NLAYER * DFFN * DMODEL / 4;
  conv_qkv3_kernel<<<(3 * NLAYER * per4 + 255) / 256, 256, 0, stream>>>(
      wq, wk, wv, wqkv_b);
  conv3_kernel<<<(NLAYER * per4 + 2 * nff4 + 255) / 256, 256, 0, stream>>>(
      wo, wo_b, fw1, fw1_b, fw2, fw2_b);
  conv_embed_kernel<<<(VPAD * DMODEL / 4 + 255) / 256, 256, 0, stream>>>(
      embed, emb_b);

  const dim3 gqkv(3 * DMODEL / 128, BT / 128);
  const dim3 gff(DFFN / 128, BT / 128);
  const dim3 gwo(DMODEL / 128, BT / 128, 4);   // wo split-K x4
  const dim3 gff2(DMODEL / 128, BT / 128, 8);  // ff2 split-K x8

  for (int i = 0; i < NLAYER; ++i) {
    if (i == 0)
      ln_kernel<0, false, true><<<BT, 256, 0, stream>>>(
          h, nullptr, nullptr, tokens, embed, pos, ln1g, ln1b, xn);
    else
      ln_kernel<8, true, false><<<BT, 256, 0, stream>>>(
          h, part, fb2 + (i - 1) * DMODEL, nullptr, nullptr, nullptr,
          ln1g + i * DMODEL, ln1b + i * DMODEL, xn);

    gemm_bf16_nt<true, false, false, false, false, false, false>
        <<<gqkv, 256, 0, stream>>>(
            xn, wqkv_b + (size_t)i * 3 * DMODEL * DMODEL, nullptr,
            tmask + i * DMODEL, nullptr, nullptr, nullptr, 0, qb, kb, vt, BT,
            DMODEL, 3 * DMODEL, DMODEL);

    fattn_kernel<<<2 * NBH * (SEQ / 64), 256, 0, stream>>>(qb, kb, vt, opart,
                                                           mlb);
    fmerge_kernel<<<NBH * SEQ / 4, 256, 0, stream>>>(opart, mlb, ab);

    gemm_bf16_nt<false, false, false, false, false, false, true>
        <<<gwo, 256, 0, stream>>>(
            ab, wo_b + (size_t)i * DMODEL * DMODEL, nullptr, nullptr, nullptr,
            nullptr, part, DMODEL, nullptr, nullptr, nullptr, BT, DMODEL,
            DMODEL, DMODEL / 4);

    ln_kernel<4, false, false><<<BT, 256, 0, stream>>>(
        h, part, nullptr, nullptr, nullptr, nullptr, ln2g + i * DMODEL,
        ln2b + i * DMODEL, xn);

    gemm_bf16_nt<false, true, true, false, true, false, false>
        <<<gff, 256, 0, stream>>>(
            xn, fw1_b + (size_t)i * DFFN * DMODEL, fb1 + i * DFFN, nullptr,
            nullptr, nullptr, ffb, DFFN, nullptr, nullptr, nullptr, BT, DMODEL,
            DFFN, DMODEL);

    gemm_bf16_nt<false, false, false, false, false, false, true>
        <<<gff2, 256, 0, stream>>>(
            ffb, fw2_b + (size_t)i * DMODEL * DFFN, nullptr, nullptr, nullptr,
            nullptr, part, DMODEL, nullptr, nullptr, nullptr, BT, DFFN, DMODEL,
            DFFN / 8);
  }

  ln_kernel<8, true, false><<<BT, 256, 0, stream>>>(
      h, part, fb2 + (NLAYER - 1) * DMODEL, nullptr, nullptr, nullptr, lnfg,
      lnfb, xn);

  gemm_lmhead<<<8 * (VPAD / 256), 512, 0, stream>>>(xn, emb_b, (float*)d_out);
}